// Round 7
// baseline (217.342 us; speedup 1.0000x reference)
//
#include <hip/hip_runtime.h>

typedef _Float16 f16;
typedef __attribute__((ext_vector_type(4))) _Float16 f16x4;
typedef __attribute__((ext_vector_type(8))) _Float16 f16x8;
typedef __attribute__((ext_vector_type(16))) float f32x16;

#define D_MODEL 1024
#define SEQ 2048
#define NBATCH 4
#define NROWS (NBATCH * SEQ)  // 8192

// ---------------------------------------------------------------- utilities
__device__ __forceinline__ void gload16(const void* g, void* l) {
  __builtin_amdgcn_global_load_lds(
      (__attribute__((address_space(1))) void*)(void*)g,
      (__attribute__((address_space(3))) void*)l, 16, 0, 0);
}

#define BARF                                   \
  do {                                         \
    asm volatile("" ::: "memory");             \
    __builtin_amdgcn_s_barrier();              \
    asm volatile("" ::: "memory");             \
  } while (0)
#define PRIO1 __builtin_amdgcn_s_setprio(1)
#define PRIO0 __builtin_amdgcn_s_setprio(0)

// ----------------------------------------------------- 32x32 2-phase core
// BM=256, BN in {256,128}, BK=64, 512 threads (8 waves = 2M x 4N),
// mfma_f32_32x32x16_f16, fp32 acc (f32x16 per 32x32 frag).
// LDS (f16 units): A half (d,h) at (d*2+h)*8192 ([128][64] swizzled);
// B: BN=256 at 32768+(d*2+h)*8192, BN=128 at 32768+d*8192.
// XOR chunk swizzle, key = row&7 for BOTH A and B (staged via pre-swizzled
// per-lane global source; read with matching XOR).
// 2 phases per K-tile; counted vmcnt (4|2), never 0 in-loop.
#define ADVA                                                      \
  {                                                               \
    if (ka < NT - 1) {                                            \
      ka++;                                                       \
      aP0 += stepA; aP1 += stepA; aP2 += stepA; aP3 += stepA;     \
    }                                                             \
  }
#define ADVB                                                      \
  {                                                               \
    if (kb < NT - 1) {                                            \
      kb++;                                                       \
      bP0 += stepB; bP1 += stepB;                                 \
      if constexpr (BN == 256) { bP2 += stepB; bP3 += stepB; }    \
    }                                                             \
  }
#define STA(SL, H)                                                \
  {                                                               \
    f16* d_ = lds + ((SL) * 2 + (H)) * 8192 + t * 8;              \
    gload16((H) ? aP2 : aP0, d_);                                 \
    gload16((H) ? aP3 : aP1, d_ + 4096);                          \
  }
#define STB_ALL(SL)                                               \
  {                                                               \
    if constexpr (BN == 256) {                                    \
      f16* d0_ = lds + 32768 + ((SL) * 2 + 0) * 8192 + t * 8;     \
      gload16(bP0, d0_);                                          \
      gload16(bP1, d0_ + 4096);                                   \
      f16* d1_ = lds + 32768 + ((SL) * 2 + 1) * 8192 + t * 8;     \
      gload16(bP2, d1_);                                          \
      gload16(bP3, d1_ + 4096);                                   \
    } else {                                                      \
      f16* d_ = lds + 32768 + (SL) * 8192 + t * 8;                \
      gload16(bP0, d_);                                           \
      gload16(bP1, d_ + 4096);                                    \
    }                                                             \
  }
#define VMC                                                       \
  {                                                               \
    if constexpr (BN == 256) {                                    \
      asm volatile("s_waitcnt vmcnt(4)" ::: "memory");            \
    } else {                                                      \
      asm volatile("s_waitcnt vmcnt(2)" ::: "memory");            \
    }                                                             \
  }
#define RDA(D, G)                                                 \
  _Pragma("unroll") for (int mf = 0; mf < 2; ++mf)                \
  _Pragma("unroll") for (int ks = 0; ks < 4; ++ks) {              \
    const int rr = ((G) * 2 + mf) * 32 + l31;                     \
    fa[mf][ks] = *(const f16x8*)(lds + ((D) * 2 + wm) * 8192 +    \
        rr * 64 + ((((ks << 1) | hi) ^ (rr & 7)) << 3));          \
  }
#define RDB(D)                                                    \
  _Pragma("unroll") for (int nf = 0; nf < NF; ++nf)               \
  _Pragma("unroll") for (int ks = 0; ks < 4; ++ks) {              \
    const int rb = wn * (BN / 4) + nf * 32 + l31;                 \
    int base_, rl_;                                               \
    if constexpr (BN == 256) {                                    \
      base_ = 32768 + ((D) * 2 + (rb >> 7)) * 8192;               \
      rl_ = rb & 127;                                             \
    } else {                                                      \
      base_ = 32768 + (D) * 8192;                                 \
      rl_ = rb;                                                   \
    }                                                             \
    fb[nf][ks] = *(const f16x8*)(lds + base_ + rl_ * 64 +         \
        ((((ks << 1) | hi) ^ (rb & 7)) << 3));                    \
  }
#define MFG(G)                                                    \
  _Pragma("unroll") for (int ks = 0; ks < 4; ++ks)                \
  _Pragma("unroll") for (int mf = 0; mf < 2; ++mf)                \
  _Pragma("unroll") for (int nf = 0; nf < NF; ++nf)               \
    acc[((G) * 2 + mf) * NF + nf] =                               \
        __builtin_amdgcn_mfma_f32_32x32x16_f16(                   \
            fa[mf][ks], fb[nf][ks], acc[((G) * 2 + mf) * NF + nf],\
            0, 0, 0);

template <int BN>
__device__ __forceinline__ void gemm32(
    const f16* aP0, const f16* aP1, const f16* aP2, const f16* aP3,
    const f16* bP0, const f16* bP1, const f16* bP2, const f16* bP3,
    int stepA, int stepB, int NT, f16* lds, f32x16* acc)
{
  constexpr int NF = BN / 128;   // 32x32 n-frags per wave
  const int t = threadIdx.x, l = t & 63;
  const int w = t >> 6, wm = w >> 2, wn = w & 3;
  const int l31 = l & 31, hi = l >> 5;
  f16x8 fa[2][4], fb[NF][4];
  f32x16 zz;
#pragma unroll
  for (int j = 0; j < 16; ++j) zz[j] = 0.f;
#pragma unroll
  for (int i = 0; i < 4 * NF; ++i) acc[i] = zz;
  int ka = 0, kb = 0;
  (void)bP2; (void)bP3;

  // prologue: A(0), B(0) -> dbuf0; B(1) -> dbuf1
  STA(0, 0); STA(0, 1); ADVA;
  STB_ALL(0); ADVB;
  STB_ALL(1); ADVB;
  VMC;   // T0 landed; B(1) in flight
  BARF;

#pragma unroll 1
  for (int kt = 0; kt < NT; ++kt) {
    const int sl = kt & 1;
    // phase 1: stage A(kt+1) -> slot sl^1; compute G=0 half
    STA(sl ^ 1, 0); STA(sl ^ 1, 1); ADVA;
    RDA(sl, 0); RDB(sl);
    PRIO1; MFG(0); PRIO0;
    BARF;
    // phase 2: stage B(kt+2) -> slot sl; counted vmcnt; compute G=1 half
    RDA(sl, 1);
    STB_ALL(sl); ADVB;
    VMC;   // A(kt+1), B(kt+1) landed; B(kt+2) in flight
    PRIO1; MFG(1); PRIO0;
    BARF;
  }
}

// ------------------- GEMM1: QKV, BN=256, grid dim3(32,12), natural order
__global__ __launch_bounds__(512, 2) void k_qkv3(
    const f16* __restrict__ srch, const f16* __restrict__ wt,
    f16* __restrict__ qp, f16* __restrict__ kp, f16* __restrict__ vp)
{
  __shared__ f16 lds[65536];
  const int t = threadIdx.x, l = t & 63;
  const int w = t >> 6, wm = w >> 2, wn = w & 3;
  const int l31 = l & 31, hi = l >> 5, c = t & 7;
  const int bx = blockIdx.x, by = blockIdx.y;
  const int z = by >> 2, cb = by & 3;
  const f16 *aP[4], *bP[4];
#pragma unroll
  for (int i = 0; i < 4; ++i) {
    const int rl = i * 64 + (t >> 3);
    aP[i] = srch + (size_t)(bx * 256 + rl) * 1024 + ((c ^ (rl & 7)) << 3);
    bP[i] = wt + ((size_t)z << 20) + (size_t)(cb * 256 + rl) * 1024 +
            ((c ^ (rl & 7)) << 3);
  }
  f32x16 acc[8];
  gemm32<256>(aP[0], aP[1], aP[2], aP[3], bP[0], bP[1], bP[2], bP[3],
              64, 64, 16, lds, acc);
  f16* dst = (z == 0) ? qp : (z == 1 ? kp : vp);
  const int rbase = bx * 256 + wm * 128 + 4 * hi;
#pragma unroll
  for (int mf = 0; mf < 4; ++mf)
#pragma unroll
    for (int nf = 0; nf < 2; ++nf) {
      const int col = cb * 256 + wn * 64 + nf * 32 + l31;
#pragma unroll
      for (int r = 0; r < 16; ++r) {
        const int row = rbase + mf * 32 + (r & 3) + 8 * (r >> 2);
        dst[(size_t)row * 1024 + col] = (f16)acc[mf * 2 + nf][r];
      }
    }
}

// --------------------------- GEMM2: scores = Qt*Kt^T/32, f16 out (gathered)
__global__ __launch_bounds__(512, 2) void k_scores(
    const f16* __restrict__ qp, const f16* __restrict__ kp,
    f16* __restrict__ abf)
{
  __shared__ f16 lds[65536];
  const int t = threadIdx.x, l = t & 63;
  const int w = t >> 6, wm = w >> 2, wn = w & 3;
  const int l31 = l & 31, hi = l >> 5, c = t & 7;
  const int b = blockIdx.z;
  const f16* qb = qp + ((size_t)b << 21);
  const f16* kb = kp + ((size_t)b << 21);
  const f16 *aP[4], *bP[4];
#pragma unroll
  for (int i = 0; i < 4; ++i) {
    const int rl = i * 64 + (t >> 3);
    const int spA = blockIdx.x * 256 + rl;
    aP[i] = qb + (size_t)((spA & 127) << 4) * 1024 + ((spA >> 7) << 6) +
            ((c ^ (rl & 7)) << 3);
    const int spB = blockIdx.y * 256 + rl;
    bP[i] = kb + (size_t)((spB & 127) << 4) * 1024 + ((spB >> 7) << 6) +
            ((c ^ (rl & 7)) << 3);
  }
  f32x16 acc[8];
  gemm32<256>(aP[0], aP[1], aP[2], aP[3], bP[0], bP[1], bP[2], bP[3],
              1024, 1024, 16, lds, acc);
  f16* Cb = abf + ((size_t)b << 22);
  const int rbase = blockIdx.x * 256 + wm * 128 + 4 * hi;
#pragma unroll
  for (int mf = 0; mf < 4; ++mf)
#pragma unroll
    for (int nf = 0; nf < 2; ++nf) {
      const int col = blockIdx.y * 256 + wn * 64 + nf * 32 + l31;
#pragma unroll
      for (int r = 0; r < 16; ++r) {
        const int row = rbase + mf * 32 + (r & 3) + 8 * (r >> 2);
        Cb[(size_t)row * 2048 + col] = (f16)(acc[mf * 2 + nf][r] * 0.03125f);
      }
    }
}

// ------------------------------------- GEMM3: att = a * Vt, f16 out, BN=128
__global__ __launch_bounds__(512, 2) void k_att(
    const f16* __restrict__ abf, const f16* __restrict__ vtT,
    f16* __restrict__ attb)
{
  __shared__ f16 lds[49152];
  const int t = threadIdx.x, l = t & 63;
  const int w = t >> 6, wm = w >> 2, wn = w & 3;
  const int l31 = l & 31, hi = l >> 5, c = t & 7;
  const int b = blockIdx.z;
  const f16* ab = abf + ((size_t)b << 22);
  const f16* vb = vtT + ((size_t)b << 21);
  const f16 *aP[4], *bP[2];
#pragma unroll
  for (int i = 0; i < 4; ++i) {
    const int rl = i * 64 + (t >> 3);
    aP[i] = ab + (size_t)(blockIdx.x * 256 + rl) * 2048 + ((c ^ (rl & 7)) << 3);
  }
#pragma unroll
  for (int i = 0; i < 2; ++i) {
    const int rl = i * 64 + (t >> 3);
    bP[i] = vb + (size_t)(blockIdx.y * 128 + rl) * 2048 +
            ((c ^ (rl & 7)) << 3);
  }
  f32x16 acc[4];
  gemm32<128>(aP[0], aP[1], aP[2], aP[3], bP[0], bP[1], bP[0], bP[0],
              64, 64, 32, lds, acc);
  f16* Cb = attb + ((size_t)b << 21);
  const int rbase = blockIdx.x * 256 + wm * 128 + 4 * hi;
  const int col = blockIdx.y * 128 + wn * 32 + l31;
#pragma unroll
  for (int mf = 0; mf < 4; ++mf)
#pragma unroll
    for (int r = 0; r < 16; ++r) {
      const int row = rbase + mf * 32 + (r & 3) + 8 * (r >> 2);
      Cb[(size_t)row * 1024 + col] = (f16)acc[mf][r];
    }
}

// ----------------- merged prep: src cast (blocks 0..4095) + W^T cast (rest)
__global__ __launch_bounds__(256) void k_prep(
    const float* __restrict__ src, const float* __restrict__ w0,
    const float* __restrict__ w1, const float* __restrict__ w2,
    f16* __restrict__ srch, f16* __restrict__ wt)
{
  const int b = blockIdx.x, t = threadIdx.x;
  if (b < 4096) {
    const size_t i = (size_t)b * 256 + t;
    const float4* p = (const float4*)src;
    float4 v0 = p[2 * i], v1 = p[2 * i + 1];
    f16x8 o;
    o[0] = (f16)v0.x; o[1] = (f16)v0.y; o[2] = (f16)v0.z; o[3] = (f16)v0.w;
    o[4] = (f16)v1.x; o[5] = (f16)v1.y; o[6] = (f16)v1.z; o[7] = (f16)v1.w;
    *(f16x8*)(srch + 8 * i) = o;
    return;
  }
  const int id = b - 4096;            // 0..767
  const int z = id >> 8, rem = id & 255;
  const int bx = rem & 15, by = rem >> 4;
  const float* in = (z == 0) ? w0 : (z == 1 ? w1 : w2);
  f16* o = wt + ((size_t)z << 20);
  __shared__ f16 tile[64][65];
  const int rr = t >> 4, c4 = (t & 15) * 4;
  const int r0 = bx * 64, c0 = by * 64;
#pragma unroll
  for (int i = 0; i < 4; ++i) {
    float4 f = *(const float4*)(in + (size_t)(r0 + rr + 16 * i) * 1024 + c0 + c4);
    tile[rr + 16 * i][c4 + 0] = (f16)f.x;
    tile[rr + 16 * i][c4 + 1] = (f16)f.y;
    tile[rr + 16 * i][c4 + 2] = (f16)f.z;
    tile[rr + 16 * i][c4 + 3] = (f16)f.w;
  }
  __syncthreads();
#pragma unroll
  for (int i = 0; i < 4; ++i) {
    const int n = c0 + rr + 16 * i;
    f16* dst = o + (size_t)n * 1024 + r0 + c4;
    dst[0] = tile[c4 + 0][rr + 16 * i];
    dst[1] = tile[c4 + 1][rr + 16 * i];
    dst[2] = tile[c4 + 2][rr + 16 * i];
    dst[3] = tile[c4 + 3][rr + 16 * i];
  }
}

// ---------- merged: softmax rows (blocks 0..8191) + V scramble-T (rest)
__global__ __launch_bounds__(256) void k_softscr(
    float* __restrict__ out, f16* __restrict__ abf,
    const f16* __restrict__ vp, f16* __restrict__ vtT)
{
  __shared__ f16 shm[64][68];
  const int t = threadIdx.x;
  if (blockIdx.x < 8192) {
    float* red = (float*)&shm[0][0];
    const size_t base = (size_t)blockIdx.x * 2048;
    const int lane = t & 63, w = t >> 6;
    f16x8 v = *(const f16x8*)(abf + base + (size_t)t * 8);
    float x[8];
#pragma unroll
    for (int j = 0; j < 8; ++j) x[j] = (float)v[j];
    float m = fmaxf(fmaxf(fmaxf(x[0], x[1]), fmaxf(x[2], x[3])),
                    fmaxf(fmaxf(x[4], x[5]), fmaxf(x[6], x[7])));
#pragma unroll
    for (int off = 1; off < 64; off <<= 1) m = fmaxf(m, __shfl_xor(m, off));
    if (lane == 0) red[w] = m;
    __syncthreads();
    m = fmaxf(fmaxf(red[0], red[1]), fmaxf(red[2], red[3]));
    float s = 0.f;
#pragma unroll
    for (int j = 0; j < 8; ++j) { x[j] = __expf(x[j] - m); s += x[j]; }
#pragma unroll
    for (int off = 1; off < 64; off <<= 1) s += __shfl_xor(s, off);
    if (lane == 0) red[4 + w] = s;
    __syncthreads();
    s = red[4] + red[5] + red[6] + red[7];
    const float inv = 1.0f / s;
#pragma unroll
    for (int j = 0; j < 8; ++j) x[j] *= inv;
    float4 o0 = {x[0], x[1], x[2], x[3]}, o1 = {x[4], x[5], x[6], x[7]};
    ((float4*)(out + base))[2 * t] = o0;
    ((float4*)(out + base))[2 * t + 1] = o1;
    f16x8 ov;
#pragma unroll
    for (int j = 0; j < 8; ++j) ov[j] = (f16)x[j];
    *(f16x8*)(abf + base + (size_t)t * 8) = ov;
    return;
  }
  const int id = blockIdx.x - 8192;           // 0..2047
  const int sx = id & 31, sy = (id >> 5) & 15, bz = id >> 9;
  const int sp0 = sx * 64, dp0 = sy * 64;
  const int d6 = dp0 >> 6;
  const int jb = (sp0 >> 7) << 6;
  const int sbase = sp0 & 127;
  const f16* srcv = vp + ((size_t)bz << 21);
  f16* dstv = vtT + ((size_t)bz << 21);
#pragma unroll
  for (int p = 0; p < 2; ++p) {
    const int u = p * 32 + (t >> 3);
    const int s = ((sbase + u) << 4) | d6;
    const int cc = (t & 7) << 3;
    f16x8 v = *(const f16x8*)(srcv + (size_t)s * 1024 + jb + cc);
    *(f16x4*)&shm[u][cc]     = f16x4{v[0], v[1], v[2], v[3]};
    *(f16x4*)&shm[u][cc + 4] = f16x4{v[4], v[5], v[6], v[7]};
  }
  __syncthreads();
#pragma unroll
  for (int p = 0; p < 2; ++p) {
    const int cc = p * 32 + (t >> 3);
    const int v0 = (t & 7) << 3;
    f16x8 o;
#pragma unroll
    for (int j = 0; j < 8; ++j) o[j] = shm[v0 + j][cc];
    *(f16x8*)(dstv + (size_t)(dp0 + cc) * 2048 + sp0 + v0) = o;
  }
}

// --------------------------------------------- fused LN1 + add + LN2
__global__ __launch_bounds__(256) void k_ln(
    const f16* __restrict__ attb, const float* __restrict__ src,
    const float* __restrict__ w1, const float* __restrict__ b1,
    const float* __restrict__ w2, const float* __restrict__ b2,
    float* __restrict__ out)
{
  const size_t base = (size_t)blockIdx.x * 1024;
  const int t = threadIdx.x, lane = t & 63, w = t >> 6;
  f16x4 a4 = ((const f16x4*)(attb + base))[t];
  float ax = (float)a4[0], ay = (float)a4[1], az = (float)a4[2], aw = (float)a4[3];
  float s = ax + ay + az + aw;
  float s2 = ax * ax + ay * ay + az * az + aw * aw;
#pragma unroll
  for (int off = 1; off < 64; off <<= 1) {
    s += __shfl_xor(s, off);
    s2 += __shfl_xor(s2, off);
  }
  __shared__ float red[16];
  if (lane == 0) { red[w] = s; red[4 + w] = s2; }
  __syncthreads();
  s = red[0] + red[1] + red[2] + red[3];
  s2 = red[4] + red[5] + red[6] + red[7];
  float mu = s * (1.0f / 1024.0f);
  float var = s2 * (1.0f / 1024.0f) - mu * mu;
  float rs = rsqrtf(var + 1e-5f);
  float4 W1 = ((const float4*)w1)[t], B1 = ((const float4*)b1)[t];
  float4 sv = ((const float4*)(src + base))[t];
  float y0 = sv.x + (ax - mu) * rs * W1.x + B1.x;
  float y1 = sv.y + (ay - mu) * rs * W1.y + B1.y;
  float y2 = sv.z + (az - mu) * rs * W1.z + B1.z;
  float y3 = sv.w + (aw - mu) * rs * W1.w + B1.w;
  s = y0 + y1 + y2 + y3;
  s2 = y0 * y0 + y1 * y1 + y2 * y2 + y3 * y3;
#pragma unroll
  for (int off = 1; off < 64; off <<= 1) {
    s += __shfl_xor(s, off);
    s2 += __shfl_xor(s2, off);
  }
  if (lane == 0) { red[8 + w] = s; red[12 + w] = s2; }
  __syncthreads();
  s = red[8] + red[9] + red[10] + red[11];
  s2 = red[12] + red[13] + red[14] + red[15];
  mu = s * (1.0f / 1024.0f);
  var = s2 * (1.0f / 1024.0f) - mu * mu;
  rs = rsqrtf(var + 1e-5f);
  float4 W2 = ((const float4*)w2)[t], B2 = ((const float4*)b2)[t];
  float4 o;
  o.x = (y0 - mu) * rs * W2.x + B2.x;
  o.y = (y1 - mu) * rs * W2.y + B2.y;
  o.z = (y2 - mu) * rs * W2.z + B2.z;
  o.w = (y3 - mu) * rs * W2.w + B2.w;
  ((float4*)(out + base))[t] = o;
}

// ---------------------------------------------------------------- launch
extern "C" void kernel_launch(void* const* d_in, const int* in_sizes, int n_in,
                              void* d_out, int out_size, void* d_ws, size_t ws_size,
                              hipStream_t stream) {
  const float* src = (const float*)d_in[0];
  const float* Wq  = (const float*)d_in[1];
  const float* Wk  = (const float*)d_in[2];
  const float* Wv  = (const float*)d_in[3];
  const float* l1w = (const float*)d_in[4];
  const float* l1b = (const float*)d_in[5];
  const float* l2w = (const float*)d_in[6];
  const float* l2b = (const float*)d_in[7];
  float* Xout = (float*)d_out;
  float* Aout = Xout + (size_t)NROWS * D_MODEL;

  // workspace layout (134 MB, non-overlapping)
  char* ws = (char*)d_ws;
  f16* srch = (f16*)ws;                       // 16 MB (8192x1024)
  f16* wt   = (f16*)(ws + (16u << 20));       //  6 MB (3072x1024, W^T)
  f16* qp   = (f16*)(ws + (22u << 20));       // 16 MB
  f16* kp   = (f16*)(ws + (38u << 20));       // 16 MB
  f16* vp   = (f16*)(ws + (54u << 20));       // 16 MB
  f16* vtT  = (f16*)(ws + (70u << 20));       // 16 MB (B,D,S scrambled-T)
  f16* abf  = (f16*)(ws + (86u << 20));       // 32 MB (B,S,S scores->a f16)
  f16* attb = (f16*)(ws + (118u << 20));      // 16 MB (B,S,D f16)

  k_prep<<<4864, 256, 0, stream>>>(src, Wq, Wk, Wv, srch, wt);
  k_qkv3<<<dim3(32, 12), 512, 0, stream>>>(srch, wt, qp, kp, vp);
  k_scores<<<dim3(8, 8, 4), 512, 0, stream>>>(qp, kp, abf);
  k_softscr<<<8192 + 2048, 256, 0, stream>>>(Aout, abf, vp, vtT);
  k_att<<<dim3(8, 8, 4), 512, 0, stream>>>(abf, vtT, attb);
  k_ln<<<NROWS, 256, 0, stream>>>(attb, src, l1w, l1b, l2w, l2b, Xout);
}

// Round 8
// 197.869 us; speedup vs baseline: 1.0984x; 1.0984x over previous
//
#include <hip/hip_runtime.h>

typedef _Float16 f16;
typedef __attribute__((ext_vector_type(2))) _Float16 f16x2;
typedef __attribute__((ext_vector_type(4))) _Float16 f16x4;
typedef __attribute__((ext_vector_type(8))) _Float16 f16x8;
typedef __attribute__((ext_vector_type(4))) float f32x4;

#define D_MODEL 1024
#define SEQ 2048
#define NBATCH 4
#define NROWS (NBATCH * SEQ)  // 8192

// ---------------------------------------------------------------- utilities
__device__ __forceinline__ void gload16(const void* g, void* l) {
  __builtin_amdgcn_global_load_lds(
      (__attribute__((address_space(1))) void*)(void*)g,
      (__attribute__((address_space(3))) void*)l, 16, 0, 0);
}

#define BARF                                   \
  do {                                         \
    asm volatile("" ::: "memory");             \
    __builtin_amdgcn_s_barrier();              \
    asm volatile("" ::: "memory");             \
  } while (0)
#define PRIO1 __builtin_amdgcn_s_setprio(1)
#define PRIO0 __builtin_amdgcn_s_setprio(0)

// ---------------------------------------------------------- 8-wave GEMM core
// (R4's best-measured 2-phase core, verbatim.)
// BM=256, BN in {256,128}, BK=64, 512 threads (8 waves = 2M x 4N), f16 MFMA
// 16x16x32, fp32 acc. LDS double-buffered slots: A[256][64] + B[BN][64],
// XOR-swizzled via pre-swizzled global source (keyA=row&7, keyB=(row>>2)&7).
// 2 phases per K-tile, ONE barrier per phase, compiler-scheduled interleave;
// counted vmcnt (4|2), never 0 in-loop.
template <int BN>
__device__ __forceinline__ void gemm8_core(
    const f16* aP0, const f16* aP1, const f16* aP2, const f16* aP3,
    const f16* bP0, const f16* bP1, const f16* bP2, const f16* bP3,
    int stepA, int stepB, int NT, f16* lds, f32x4* acc)
{
  constexpr int NJ = BN / 128;           // n-frag pairs per n-half (2|1)
  constexpr int NACC = 2 * NJ;           // acc columns (4|2)
  constexpr int SLOT = 16384 + BN * 64;  // f16 units per slot
  const int t = threadIdx.x, l = t & 63;
  const int w = t >> 6, wm = w >> 2, wn = w & 3;
  const int fr = l & 15, g0 = l >> 4;

  int aof[2][4][2], bof[2][NJ][2];
#pragma unroll
  for (int mh = 0; mh < 2; ++mh)
#pragma unroll
    for (int mi = 0; mi < 4; ++mi)
#pragma unroll
      for (int kh = 0; kh < 2; ++kh) {
        const int ra = wm * 128 + mh * 64 + mi * 16 + fr;
        aof[mh][mi][kh] = ra * 64 + (((g0 + kh * 4) ^ (ra & 7)) << 3);
      }
#pragma unroll
  for (int nh = 0; nh < 2; ++nh)
#pragma unroll
    for (int j = 0; j < NJ; ++j)
#pragma unroll
      for (int kh = 0; kh < 2; ++kh) {
        const int rb = (BN == 256) ? (wn * 64 + fr * 4 + nh * 2 + j)
                                   : (wn * 32 + fr * 2 + nh);
        bof[nh][j][kh] = rb * 64 + (((g0 + kh * 4) ^ ((rb >> 2) & 7)) << 3);
      }
#pragma unroll
  for (int i = 0; i < 8 * NACC; ++i) acc[i] = f32x4{0.f, 0.f, 0.f, 0.f};

  f16x8 fa[4][2];
  f16x8 fb[2][NJ][2];

#define STAGE_A(SL)                                  \
  {                                                  \
    f16* d = lds + (SL) * SLOT + t * 8;              \
    gload16(aP0, d);                                 \
    gload16(aP1, d + 4096);                          \
    gload16(aP2, d + 8192);                          \
    gload16(aP3, d + 12288);                         \
  }
#define STAGE_B(SL)                                  \
  {                                                  \
    f16* d = lds + (SL) * SLOT + 16384 + t * 8;      \
    gload16(bP0, d);                                 \
    gload16(bP1, d + 4096);                          \
    if constexpr (BN == 256) {                       \
      gload16(bP2, d + 8192);                        \
      gload16(bP3, d + 12288);                       \
    }                                                \
  }
#define ADVA { aP0 += stepA; aP1 += stepA; aP2 += stepA; aP3 += stepA; }
#define ADVB                                         \
  {                                                  \
    bP0 += stepB; bP1 += stepB;                      \
    if constexpr (BN == 256) { bP2 += stepB; bP3 += stepB; } \
  }
#define VMC                                                        \
  if constexpr (BN == 256) {                                       \
    asm volatile("s_waitcnt vmcnt(4)" ::: "memory");               \
  } else {                                                         \
    asm volatile("s_waitcnt vmcnt(2)" ::: "memory");               \
  }
#define LOAD_A(MH)                                   \
  _Pragma("unroll") for (int mi = 0; mi < 4; ++mi)   \
  _Pragma("unroll") for (int kh = 0; kh < 2; ++kh)   \
      fa[mi][kh] = *(const f16x8*)(LA + aof[MH][mi][kh]);
#define LOAD_B(NH)                                   \
  _Pragma("unroll") for (int j = 0; j < NJ; ++j)     \
  _Pragma("unroll") for (int kh = 0; kh < 2; ++kh)   \
      fb[NH][j][kh] = *(const f16x8*)(LBp + bof[NH][j][kh]);
#define MFMA_BLK(MH, NH)                                                    \
  _Pragma("unroll") for (int mi = 0; mi < 4; ++mi)                          \
  _Pragma("unroll") for (int j = 0; j < NJ; ++j)                            \
  _Pragma("unroll") for (int kh = 0; kh < 2; ++kh)                          \
      acc[((MH)*4 + mi) * NACC + (NH)*NJ + j] =                             \
          __builtin_amdgcn_mfma_f32_16x16x32_f16(                           \
              fa[mi][kh], fb[NH][j][kh],                                    \
              acc[((MH)*4 + mi) * NACC + (NH)*NJ + j], 0, 0, 0);

  (void)bP2; (void)bP3;
  // prologue: A(0)->slot0, B(0)->slot0, B(1)->slot1; wait A0,B0 landed.
  STAGE_A(0); ADVA;              // aP -> tile 1
  STAGE_B(0); ADVB;
  STAGE_B(1); ADVB;              // bP -> tile 2
  VMC;                           // allow B(1) outstanding only
  BARF;

  for (int kt = 0; kt < NT; ++kt) {
    const int sl = kt & 1;
    const f16* LA = lds + sl * SLOT;
    const f16* LBp = LA + 16384;
    // ---- phase 1
    STAGE_A(sl ^ 1);             // tile kt+1's A (region last read kt-1.p2)
    if (kt + 2 < NT) ADVA;
    LOAD_A(0); LOAD_B(0); LOAD_B(1);
    PRIO1; MFMA_BLK(0, 0); MFMA_BLK(0, 1); PRIO0;
    BARF;
    // ---- phase 2
    LOAD_A(1);
    STAGE_B(sl);                 // tile kt+2's B (region last read kt.p1)
    if (kt + 3 < NT) ADVB;
    VMC;                         // A(kt+1), B(kt+1) landed; B(kt+2) in flight
    PRIO1; MFMA_BLK(1, 0); MFMA_BLK(1, 1); PRIO0;
    BARF;
  }
#undef STAGE_A
#undef STAGE_B
#undef ADVA
#undef ADVB
#undef VMC
#undef LOAD_A
#undef LOAD_B
#undef MFMA_BLK
}

// ------------------------------------------- GEMM1: QKV, BN=128, grid 32x24
__global__ __launch_bounds__(512, 2) void k_qkv3(
    const f16* __restrict__ srch, const f16* __restrict__ wt,
    f16* __restrict__ qp, f16* __restrict__ kp, f16* __restrict__ vp)
{
  __shared__ f16 lds[2 * (16384 + 128 * 64)];
  const int t = threadIdx.x, l = t & 63;
  const int w = t >> 6, wm = w >> 2, wn = w & 3;
  const int fr = l & 15, g0 = l >> 4, c = t & 7;
  const int z = blockIdx.y >> 3, cb = blockIdx.y & 7;
  const f16 *aP[4], *bP[2];
#pragma unroll
  for (int i = 0; i < 4; ++i) {
    const int rl = i * 64 + (t >> 3);
    aP[i] = srch + (size_t)(blockIdx.x * 256 + rl) * 1024 + ((c ^ (rl & 7)) << 3);
  }
#pragma unroll
  for (int i = 0; i < 2; ++i) {
    const int rl = i * 64 + (t >> 3);
    bP[i] = wt + ((size_t)z << 20) + (size_t)(cb * 128 + rl) * 1024 +
            ((c ^ ((rl >> 2) & 7)) << 3);
  }
  f32x4 acc[16];
  gemm8_core<128>(aP[0], aP[1], aP[2], aP[3], bP[0], bP[1], bP[0], bP[0],
                  64, 64, 16, lds, acc);
  f16* dst = (z == 0) ? qp : (z == 1 ? kp : vp);
  const int col = cb * 128 + wn * 32 + fr * 2;
#pragma unroll
  for (int mi = 0; mi < 8; ++mi)
#pragma unroll
    for (int q = 0; q < 4; ++q) {
      const int row = blockIdx.x * 256 + wm * 128 + mi * 16 + g0 * 4 + q;
      f16x2 o = {(f16)acc[mi * 2 + 0][q], (f16)acc[mi * 2 + 1][q]};
      *(f16x2*)(dst + (size_t)row * 1024 + col) = o;
    }
}

// --------------------------- GEMM2: scores = Qt*Kt^T/32, f16 out (gathered)
__global__ __launch_bounds__(512, 2) void k_scores(
    const f16* __restrict__ qp, const f16* __restrict__ kp,
    f16* __restrict__ abf)
{
  __shared__ f16 lds[2 * (16384 + 256 * 64)];
  const int t = threadIdx.x, l = t & 63;
  const int w = t >> 6, wm = w >> 2, wn = w & 3;
  const int fr = l & 15, g0 = l >> 4, c = t & 7;
  const int b = blockIdx.z;
  const f16* qb = qp + ((size_t)b << 21);
  const f16* kb = kp + ((size_t)b << 21);
  const f16 *aP[4], *bP[4];
#pragma unroll
  for (int i = 0; i < 4; ++i) {
    const int rl = i * 64 + (t >> 3);
    const int spA = blockIdx.x * 256 + rl;
    aP[i] = qb + (size_t)((spA & 127) << 4) * 1024 + ((spA >> 7) << 6) +
            ((c ^ (rl & 7)) << 3);
    const int spB = blockIdx.y * 256 + rl;
    bP[i] = kb + (size_t)((spB & 127) << 4) * 1024 + ((spB >> 7) << 6) +
            ((c ^ ((rl >> 2) & 7)) << 3);
  }
  f32x4 acc[32];
  gemm8_core<256>(aP[0], aP[1], aP[2], aP[3], bP[0], bP[1], bP[2], bP[3],
                  1024, 1024, 16, lds, acc);
  f16* Cb = abf + ((size_t)b << 22);
  const int col = blockIdx.y * 256 + wn * 64 + fr * 4;
#pragma unroll
  for (int mi = 0; mi < 8; ++mi)
#pragma unroll
    for (int q = 0; q < 4; ++q) {
      const int row = blockIdx.x * 256 + wm * 128 + mi * 16 + g0 * 4 + q;
      f16x4 o = {(f16)(acc[mi * 4 + 0][q] * 0.03125f),
                 (f16)(acc[mi * 4 + 1][q] * 0.03125f),
                 (f16)(acc[mi * 4 + 2][q] * 0.03125f),
                 (f16)(acc[mi * 4 + 3][q] * 0.03125f)};
      *(f16x4*)(Cb + (size_t)row * 2048 + col) = o;
    }
}

// ------------------------------------- GEMM3: att = a * Vt, f16 out, BN=128
__global__ __launch_bounds__(512, 2) void k_att(
    const f16* __restrict__ abf, const f16* __restrict__ vtT,
    f16* __restrict__ attb)
{
  __shared__ f16 lds[2 * (16384 + 128 * 64)];
  const int t = threadIdx.x, l = t & 63;
  const int w = t >> 6, wm = w >> 2, wn = w & 3;
  const int fr = l & 15, g0 = l >> 4, c = t & 7;
  const int b = blockIdx.z;
  const f16* ab = abf + ((size_t)b << 22);
  const f16* vb = vtT + ((size_t)b << 21);
  const f16 *aP[4], *bP[2];
#pragma unroll
  for (int i = 0; i < 4; ++i) {
    const int rl = i * 64 + (t >> 3);
    aP[i] = ab + (size_t)(blockIdx.x * 256 + rl) * 2048 + ((c ^ (rl & 7)) << 3);
  }
#pragma unroll
  for (int i = 0; i < 2; ++i) {
    const int rl = i * 64 + (t >> 3);
    bP[i] = vb + (size_t)(blockIdx.y * 128 + rl) * 2048 +
            ((c ^ ((rl >> 2) & 7)) << 3);
  }
  f32x4 acc[16];
  gemm8_core<128>(aP[0], aP[1], aP[2], aP[3], bP[0], bP[1], bP[0], bP[0],
                  64, 64, 32, lds, acc);
  f16* Cb = attb + ((size_t)b << 21);
  const int col = blockIdx.y * 128 + wn * 32 + fr * 2;
#pragma unroll
  for (int mi = 0; mi < 8; ++mi)
#pragma unroll
    for (int q = 0; q < 4; ++q) {
      const int row = blockIdx.x * 256 + wm * 128 + mi * 16 + g0 * 4 + q;
      f16x2 o = {(f16)acc[mi * 2 + 0][q], (f16)acc[mi * 2 + 1][q]};
      *(f16x2*)(Cb + (size_t)row * 1024 + col) = o;
    }
}

// ----------------- merged prep: src cast (blocks 0..4095) + W^T cast (rest)
__global__ __launch_bounds__(256) void k_prep(
    const float* __restrict__ src, const float* __restrict__ w0,
    const float* __restrict__ w1, const float* __restrict__ w2,
    f16* __restrict__ srch, f16* __restrict__ wt)
{
  const int b = blockIdx.x, t = threadIdx.x;
  if (b < 4096) {
    const size_t i = (size_t)b * 256 + t;
    const float4* p = (const float4*)src;
    float4 v0 = p[2 * i], v1 = p[2 * i + 1];
    f16x8 o;
    o[0] = (f16)v0.x; o[1] = (f16)v0.y; o[2] = (f16)v0.z; o[3] = (f16)v0.w;
    o[4] = (f16)v1.x; o[5] = (f16)v1.y; o[6] = (f16)v1.z; o[7] = (f16)v1.w;
    *(f16x8*)(srch + 8 * i) = o;
    return;
  }
  const int id = b - 4096;            // 0..767
  const int z = id >> 8, rem = id & 255;
  const int bx = rem & 15, by = rem >> 4;
  const float* in = (z == 0) ? w0 : (z == 1 ? w1 : w2);
  f16* o = wt + ((size_t)z << 20);
  __shared__ f16 tile[64][65];
  const int rr = t >> 4, c4 = (t & 15) * 4;
  const int r0 = bx * 64, c0 = by * 64;
#pragma unroll
  for (int i = 0; i < 4; ++i) {
    float4 f = *(const float4*)(in + (size_t)(r0 + rr + 16 * i) * 1024 + c0 + c4);
    tile[rr + 16 * i][c4 + 0] = (f16)f.x;
    tile[rr + 16 * i][c4 + 1] = (f16)f.y;
    tile[rr + 16 * i][c4 + 2] = (f16)f.z;
    tile[rr + 16 * i][c4 + 3] = (f16)f.w;
  }
  __syncthreads();
#pragma unroll
  for (int i = 0; i < 4; ++i) {
    const int n = c0 + rr + 16 * i;
    f16* dst = o + (size_t)n * 1024 + r0 + c4;
    dst[0] = tile[c4 + 0][rr + 16 * i];
    dst[1] = tile[c4 + 1][rr + 16 * i];
    dst[2] = tile[c4 + 2][rr + 16 * i];
    dst[3] = tile[c4 + 3][rr + 16 * i];
  }
}

// ---------- merged: softmax rows (blocks 0..8191) + V scramble-T (rest)
__global__ __launch_bounds__(256) void k_softscr(
    float* __restrict__ out, f16* __restrict__ abf,
    const f16* __restrict__ vp, f16* __restrict__ vtT)
{
  __shared__ f16 shm[64][68];
  const int t = threadIdx.x;
  if (blockIdx.x < 8192) {
    float* red = (float*)&shm[0][0];
    const size_t base = (size_t)blockIdx.x * 2048;
    const int lane = t & 63, w = t >> 6;
    f16x8 v = *(const f16x8*)(abf + base + (size_t)t * 8);
    float x[8];
#pragma unroll
    for (int j = 0; j < 8; ++j) x[j] = (float)v[j];
    float m = fmaxf(fmaxf(fmaxf(x[0], x[1]), fmaxf(x[2], x[3])),
                    fmaxf(fmaxf(x[4], x[5]), fmaxf(x[6], x[7])));
#pragma unroll
    for (int off = 1; off < 64; off <<= 1) m = fmaxf(m, __shfl_xor(m, off));
    if (lane == 0) red[w] = m;
    __syncthreads();
    m = fmaxf(fmaxf(red[0], red[1]), fmaxf(red[2], red[3]));
    float s = 0.f;
#pragma unroll
    for (int j = 0; j < 8; ++j) { x[j] = __expf(x[j] - m); s += x[j]; }
#pragma unroll
    for (int off = 1; off < 64; off <<= 1) s += __shfl_xor(s, off);
    if (lane == 0) red[4 + w] = s;
    __syncthreads();
    s = red[4] + red[5] + red[6] + red[7];
    const float inv = 1.0f / s;
#pragma unroll
    for (int j = 0; j < 8; ++j) x[j] *= inv;
    float4 o0 = {x[0], x[1], x[2], x[3]}, o1 = {x[4], x[5], x[6], x[7]};
    ((float4*)(out + base))[2 * t] = o0;
    ((float4*)(out + base))[2 * t + 1] = o1;
    f16x8 ov;
#pragma unroll
    for (int j = 0; j < 8; ++j) ov[j] = (f16)x[j];
    *(f16x8*)(abf + base + (size_t)t * 8) = ov;
    return;
  }
  const int id = blockIdx.x - 8192;           // 0..2047
  const int sx = id & 31, sy = (id >> 5) & 15, bz = id >> 9;
  const int sp0 = sx * 64, dp0 = sy * 64;
  const int d6 = dp0 >> 6;
  const int jb = (sp0 >> 7) << 6;
  const int sbase = sp0 & 127;
  const f16* srcv = vp + ((size_t)bz << 21);
  f16* dstv = vtT + ((size_t)bz << 21);
#pragma unroll
  for (int p = 0; p < 2; ++p) {
    const int u = p * 32 + (t >> 3);
    const int s = ((sbase + u) << 4) | d6;
    const int cc = (t & 7) << 3;
    f16x8 v = *(const f16x8*)(srcv + (size_t)s * 1024 + jb + cc);
    *(f16x4*)&shm[u][cc]     = f16x4{v[0], v[1], v[2], v[3]};
    *(f16x4*)&shm[u][cc + 4] = f16x4{v[4], v[5], v[6], v[7]};
  }
  __syncthreads();
#pragma unroll
  for (int p = 0; p < 2; ++p) {
    const int cc = p * 32 + (t >> 3);
    const int v0 = (t & 7) << 3;
    f16x8 o;
#pragma unroll
    for (int j = 0; j < 8; ++j) o[j] = shm[v0 + j][cc];
    *(f16x8*)(dstv + (size_t)(dp0 + cc) * 2048 + sp0 + v0) = o;
  }
}

// --------------------------------------------- fused LN1 + add + LN2
__global__ __launch_bounds__(256) void k_ln(
    const f16* __restrict__ attb, const float* __restrict__ src,
    const float* __restrict__ w1, const float* __restrict__ b1,
    const float* __restrict__ w2, const float* __restrict__ b2,
    float* __restrict__ out)
{
  const size_t base = (size_t)blockIdx.x * 1024;
  const int t = threadIdx.x, lane = t & 63, w = t >> 6;
  f16x4 a4 = ((const f16x4*)(attb + base))[t];
  float ax = (float)a4[0], ay = (float)a4[1], az = (float)a4[2], aw = (float)a4[3];
  float s = ax + ay + az + aw;
  float s2 = ax * ax + ay * ay + az * az + aw * aw;
#pragma unroll
  for (int off = 1; off < 64; off <<= 1) {
    s += __shfl_xor(s, off);
    s2 += __shfl_xor(s2, off);
  }
  __shared__ float red[16];
  if (lane == 0) { red[w] = s; red[4 + w] = s2; }
  __syncthreads();
  s = red[0] + red[1] + red[2] + red[3];
  s2 = red[4] + red[5] + red[6] + red[7];
  float mu = s * (1.0f / 1024.0f);
  float var = s2 * (1.0f / 1024.0f) - mu * mu;
  float rs = rsqrtf(var + 1e-5f);
  float4 W1 = ((const float4*)w1)[t], B1 = ((const float4*)b1)[t];
  float4 sv = ((const float4*)(src + base))[t];
  float y0 = sv.x + (ax - mu) * rs * W1.x + B1.x;
  float y1 = sv.y + (ay - mu) * rs * W1.y + B1.y;
  float y2 = sv.z + (az - mu) * rs * W1.z + B1.z;
  float y3 = sv.w + (aw - mu) * rs * W1.w + B1.w;
  s = y0 + y1 + y2 + y3;
  s2 = y0 * y0 + y1 * y1 + y2 * y2 + y3 * y3;
#pragma unroll
  for (int off = 1; off < 64; off <<= 1) {
    s += __shfl_xor(s, off);
    s2 += __shfl_xor(s2, off);
  }
  if (lane == 0) { red[8 + w] = s; red[12 + w] = s2; }
  __syncthreads();
  s = red[8] + red[9] + red[10] + red[11];
  s2 = red[12] + red[13] + red[14] + red[15];
  mu = s * (1.0f / 1024.0f);
  var = s2 * (1.0f / 1024.0f) - mu * mu;
  rs = rsqrtf(var + 1e-5f);
  float4 W2 = ((const float4*)w2)[t], B2 = ((const float4*)b2)[t];
  float4 o;
  o.x = (y0 - mu) * rs * W2.x + B2.x;
  o.y = (y1 - mu) * rs * W2.y + B2.y;
  o.z = (y2 - mu) * rs * W2.z + B2.z;
  o.w = (y3 - mu) * rs * W2.w + B2.w;
  ((float4*)(out + base))[t] = o;
}

// ---------------------------------------------------------------- launch
extern "C" void kernel_launch(void* const* d_in, const int* in_sizes, int n_in,
                              void* d_out, int out_size, void* d_ws, size_t ws_size,
                              hipStream_t stream) {
  const float* src = (const float*)d_in[0];
  const float* Wq  = (const float*)d_in[1];
  const float* Wk  = (const float*)d_in[2];
  const float* Wv  = (const float*)d_in[3];
  const float* l1w = (const float*)d_in[4];
  const float* l1b = (const float*)d_in[5];
  const float* l2w = (const float*)d_in[6];
  const float* l2b = (const float*)d_in[7];
  float* Xout = (float*)d_out;
  float* Aout = Xout + (size_t)NROWS * D_MODEL;

  // workspace layout (134 MB, non-overlapping)
  char* ws = (char*)d_ws;
  f16* srch = (f16*)ws;                       // 16 MB (8192x1024)
  f16* wt   = (f16*)(ws + (16u << 20));       //  6 MB (3072x1024, W^T)
  f16* qp   = (f16*)(ws + (22u << 20));       // 16 MB
  f16* kp   = (f16*)(ws + (38u << 20));       // 16 MB
  f16* vp   = (f16*)(ws + (54u << 20));       // 16 MB
  f16* vtT  = (f16*)(ws + (70u << 20));       // 16 MB (B,D,S scrambled-T)
  f16* abf  = (f16*)(ws + (86u << 20));       // 32 MB (B,S,S scores->a f16)
  f16* attb = (f16*)(ws + (118u << 20));      // 16 MB (B,S,D f16)

  k_prep<<<4864, 256, 0, stream>>>(src, Wq, Wk, Wv, srch, wt);
  k_qkv3<<<dim3(32, 24), 512, 0, stream>>>(srch, wt, qp, kp, vp);
  k_scores<<<dim3(8, 8, 4), 512, 0, stream>>>(qp, kp, abf);
  k_softscr<<<8192 + 2048, 256, 0, stream>>>(Aout, abf, vp, vtT);
  k_att<<<dim3(8, 8, 4), 512, 0, stream>>>(abf, vtT, attb);
  k_ln<<<NROWS, 256, 0, stream>>>(attb, src, l1w, l1b, l2w, l2b, Xout);
}

// Round 9
// 194.206 us; speedup vs baseline: 1.1191x; 1.0189x over previous
//
#include <hip/hip_runtime.h>

typedef _Float16 f16;
typedef __attribute__((ext_vector_type(2))) _Float16 f16x2;
typedef __attribute__((ext_vector_type(4))) _Float16 f16x4;
typedef __attribute__((ext_vector_type(8))) _Float16 f16x8;
typedef __attribute__((ext_vector_type(4))) float f32x4;

#define D_MODEL 1024
#define SEQ 2048
#define NBATCH 4
#define NROWS (NBATCH * SEQ)  // 8192

// ---------------------------------------------------------------- utilities
__device__ __forceinline__ void gload16(const void* g, void* l) {
  __builtin_amdgcn_global_load_lds(
      (__attribute__((address_space(1))) void*)(void*)g,
      (__attribute__((address_space(3))) void*)l, 16, 0, 0);
}

#define BARF                                   \
  do {                                         \
    asm volatile("" ::: "memory");             \
    __builtin_amdgcn_s_barrier();              \
    asm volatile("" ::: "memory");             \
  } while (0)
#define PRIO1 __builtin_amdgcn_s_setprio(1)
#define PRIO0 __builtin_amdgcn_s_setprio(0)

// ---------------------------------------------------------- 8-wave GEMM core
// (R4/R8 best-measured 2-phase core, verbatim.)
// BM=256, BN in {256,128}, BK=64, 512 threads (8 waves = 2M x 4N), f16 MFMA
// 16x16x32, fp32 acc. LDS double-buffered slots: A[256][64] + B[BN][64],
// XOR-swizzled via pre-swizzled global source (keyA=row&7, keyB=(row>>2)&7).
// 2 phases per K-tile, ONE barrier per phase, compiler-scheduled interleave;
// counted vmcnt (4|2), never 0 in-loop.
template <int BN>
__device__ __forceinline__ void gemm8_core(
    const f16* aP0, const f16* aP1, const f16* aP2, const f16* aP3,
    const f16* bP0, const f16* bP1, const f16* bP2, const f16* bP3,
    int stepA, int stepB, int NT, f16* lds, f32x4* acc)
{
  constexpr int NJ = BN / 128;           // n-frag pairs per n-half (2|1)
  constexpr int NACC = 2 * NJ;           // acc columns (4|2)
  constexpr int SLOT = 16384 + BN * 64;  // f16 units per slot
  const int t = threadIdx.x, l = t & 63;
  const int w = t >> 6, wm = w >> 2, wn = w & 3;
  const int fr = l & 15, g0 = l >> 4;

  int aof[2][4][2], bof[2][NJ][2];
#pragma unroll
  for (int mh = 0; mh < 2; ++mh)
#pragma unroll
    for (int mi = 0; mi < 4; ++mi)
#pragma unroll
      for (int kh = 0; kh < 2; ++kh) {
        const int ra = wm * 128 + mh * 64 + mi * 16 + fr;
        aof[mh][mi][kh] = ra * 64 + (((g0 + kh * 4) ^ (ra & 7)) << 3);
      }
#pragma unroll
  for (int nh = 0; nh < 2; ++nh)
#pragma unroll
    for (int j = 0; j < NJ; ++j)
#pragma unroll
      for (int kh = 0; kh < 2; ++kh) {
        const int rb = (BN == 256) ? (wn * 64 + fr * 4 + nh * 2 + j)
                                   : (wn * 32 + fr * 2 + nh);
        bof[nh][j][kh] = rb * 64 + (((g0 + kh * 4) ^ ((rb >> 2) & 7)) << 3);
      }
#pragma unroll
  for (int i = 0; i < 8 * NACC; ++i) acc[i] = f32x4{0.f, 0.f, 0.f, 0.f};

  f16x8 fa[4][2];
  f16x8 fb[2][NJ][2];

#define STAGE_A(SL)                                  \
  {                                                  \
    f16* d = lds + (SL) * SLOT + t * 8;              \
    gload16(aP0, d);                                 \
    gload16(aP1, d + 4096);                          \
    gload16(aP2, d + 8192);                          \
    gload16(aP3, d + 12288);                         \
  }
#define STAGE_B(SL)                                  \
  {                                                  \
    f16* d = lds + (SL) * SLOT + 16384 + t * 8;      \
    gload16(bP0, d);                                 \
    gload16(bP1, d + 4096);                          \
    if constexpr (BN == 256) {                       \
      gload16(bP2, d + 8192);                        \
      gload16(bP3, d + 12288);                       \
    }                                                \
  }
#define ADVA { aP0 += stepA; aP1 += stepA; aP2 += stepA; aP3 += stepA; }
#define ADVB                                         \
  {                                                  \
    bP0 += stepB; bP1 += stepB;                      \
    if constexpr (BN == 256) { bP2 += stepB; bP3 += stepB; } \
  }
#define VMC                                                        \
  if constexpr (BN == 256) {                                       \
    asm volatile("s_waitcnt vmcnt(4)" ::: "memory");               \
  } else {                                                         \
    asm volatile("s_waitcnt vmcnt(2)" ::: "memory");               \
  }
#define LOAD_A(MH)                                   \
  _Pragma("unroll") for (int mi = 0; mi < 4; ++mi)   \
  _Pragma("unroll") for (int kh = 0; kh < 2; ++kh)   \
      fa[mi][kh] = *(const f16x8*)(LA + aof[MH][mi][kh]);
#define LOAD_B(NH)                                   \
  _Pragma("unroll") for (int j = 0; j < NJ; ++j)     \
  _Pragma("unroll") for (int kh = 0; kh < 2; ++kh)   \
      fb[NH][j][kh] = *(const f16x8*)(LBp + bof[NH][j][kh]);
#define MFMA_BLK(MH, NH)                                                    \
  _Pragma("unroll") for (int mi = 0; mi < 4; ++mi)                          \
  _Pragma("unroll") for (int j = 0; j < NJ; ++j)                            \
  _Pragma("unroll") for (int kh = 0; kh < 2; ++kh)                          \
      acc[((MH)*4 + mi) * NACC + (NH)*NJ + j] =                             \
          __builtin_amdgcn_mfma_f32_16x16x32_f16(                           \
              fa[mi][kh], fb[NH][j][kh],                                    \
              acc[((MH)*4 + mi) * NACC + (NH)*NJ + j], 0, 0, 0);

  (void)bP2; (void)bP3;
  // prologue: A(0)->slot0, B(0)->slot0, B(1)->slot1; wait A0,B0 landed.
  STAGE_A(0); ADVA;              // aP -> tile 1
  STAGE_B(0); ADVB;
  STAGE_B(1); ADVB;              // bP -> tile 2
  VMC;                           // allow B(1) outstanding only
  BARF;

  for (int kt = 0; kt < NT; ++kt) {
    const int sl = kt & 1;
    const f16* LA = lds + sl * SLOT;
    const f16* LBp = LA + 16384;
    // ---- phase 1
    STAGE_A(sl ^ 1);             // tile kt+1's A (region last read kt-1.p2)
    if (kt + 2 < NT) ADVA;
    LOAD_A(0); LOAD_B(0); LOAD_B(1);
    PRIO1; MFMA_BLK(0, 0); MFMA_BLK(0, 1); PRIO0;
    BARF;
    // ---- phase 2
    LOAD_A(1);
    STAGE_B(sl);                 // tile kt+2's B (region last read kt.p1)
    if (kt + 3 < NT) ADVB;
    VMC;                         // A(kt+1), B(kt+1) landed; B(kt+2) in flight
    PRIO1; MFMA_BLK(1, 0); MFMA_BLK(1, 1); PRIO0;
    BARF;
  }
#undef STAGE_A
#undef STAGE_B
#undef ADVA
#undef ADVB
#undef VMC
#undef LOAD_A
#undef LOAD_B
#undef MFMA_BLK
}

// ------------------------------------------- GEMM1: QKV, BN=128, grid 32x24
__global__ __launch_bounds__(512, 2) void k_qkv3(
    const f16* __restrict__ srch, const f16* __restrict__ wt,
    f16* __restrict__ qp, f16* __restrict__ kp, f16* __restrict__ vp)
{
  __shared__ f16 lds[2 * (16384 + 128 * 64)];
  const int t = threadIdx.x, l = t & 63;
  const int w = t >> 6, wm = w >> 2, wn = w & 3;
  const int fr = l & 15, g0 = l >> 4, c = t & 7;
  const int z = blockIdx.y >> 3, cb = blockIdx.y & 7;
  const f16 *aP[4], *bP[2];
#pragma unroll
  for (int i = 0; i < 4; ++i) {
    const int rl = i * 64 + (t >> 3);
    aP[i] = srch + (size_t)(blockIdx.x * 256 + rl) * 1024 + ((c ^ (rl & 7)) << 3);
  }
#pragma unroll
  for (int i = 0; i < 2; ++i) {
    const int rl = i * 64 + (t >> 3);
    bP[i] = wt + ((size_t)z << 20) + (size_t)(cb * 128 + rl) * 1024 +
            ((c ^ ((rl >> 2) & 7)) << 3);
  }
  f32x4 acc[16];
  gemm8_core<128>(aP[0], aP[1], aP[2], aP[3], bP[0], bP[1], bP[0], bP[0],
                  64, 64, 16, lds, acc);
  f16* dst = (z == 0) ? qp : (z == 1 ? kp : vp);
  const int col = cb * 128 + wn * 32 + fr * 2;
#pragma unroll
  for (int mi = 0; mi < 8; ++mi)
#pragma unroll
    for (int q = 0; q < 4; ++q) {
      const int row = blockIdx.x * 256 + wm * 128 + mi * 16 + g0 * 4 + q;
      f16x2 o = {(f16)acc[mi * 2 + 0][q], (f16)acc[mi * 2 + 1][q]};
      *(f16x2*)(dst + (size_t)row * 1024 + col) = o;
    }
}

// --------------------------- GEMM2: scores = Qt*Kt^T/32, f16 out (gathered)
// 1-D grid 256, chunked XCD swizzle: each XCD owns one batch's panel set
// (kb slice 2MB -> L2-resident across its by reuse).
__global__ __launch_bounds__(512, 2) void k_scores(
    const f16* __restrict__ qp, const f16* __restrict__ kp,
    f16* __restrict__ abf)
{
  __shared__ f16 lds[2 * (16384 + 256 * 64)];
  const int t = threadIdx.x, l = t & 63;
  const int w = t >> 6, wm = w >> 2, wn = w & 3;
  const int fr = l & 15, g0 = l >> 4, c = t & 7;
  // chunked XCD mapping: wg = xcd*32 + idx; decode z(b), by, bx
  const int id = blockIdx.x;
  const int wg = ((id & 7) << 5) + (id >> 3);
  const int b = wg >> 6, by = (wg >> 3) & 7, bx = wg & 7;
  const f16* qb = qp + ((size_t)b << 21);
  const f16* kb = kp + ((size_t)b << 21);
  const f16 *aP[4], *bP[4];
#pragma unroll
  for (int i = 0; i < 4; ++i) {
    const int rl = i * 64 + (t >> 3);
    const int spA = bx * 256 + rl;
    aP[i] = qb + (size_t)((spA & 127) << 4) * 1024 + ((spA >> 7) << 6) +
            ((c ^ (rl & 7)) << 3);
    const int spB = by * 256 + rl;
    bP[i] = kb + (size_t)((spB & 127) << 4) * 1024 + ((spB >> 7) << 6) +
            ((c ^ ((rl >> 2) & 7)) << 3);
  }
  f32x4 acc[32];
  gemm8_core<256>(aP[0], aP[1], aP[2], aP[3], bP[0], bP[1], bP[2], bP[3],
                  1024, 1024, 16, lds, acc);
  f16* Cb = abf + ((size_t)b << 22);
  const int col = by * 256 + wn * 64 + fr * 4;
#pragma unroll
  for (int mi = 0; mi < 8; ++mi)
#pragma unroll
    for (int q = 0; q < 4; ++q) {
      const int row = bx * 256 + wm * 128 + mi * 16 + g0 * 4 + q;
      f16x4 o = {(f16)(acc[mi * 4 + 0][q] * 0.03125f),
                 (f16)(acc[mi * 4 + 1][q] * 0.03125f),
                 (f16)(acc[mi * 4 + 2][q] * 0.03125f),
                 (f16)(acc[mi * 4 + 3][q] * 0.03125f)};
      *(f16x4*)(Cb + (size_t)row * 2048 + col) = o;
    }
}

// ------------------------------------- GEMM3: att = a * Vt, f16 out, BN=128
// 1-D grid 256, chunked XCD swizzle: each XCD owns one batch (vtT slice 2MB
// L2-resident across its bx reuse).
__global__ __launch_bounds__(512, 2) void k_att(
    const f16* __restrict__ abf, const f16* __restrict__ vtT,
    f16* __restrict__ attb)
{
  __shared__ f16 lds[2 * (16384 + 128 * 64)];
  const int t = threadIdx.x, l = t & 63;
  const int w = t >> 6, wm = w >> 2, wn = w & 3;
  const int fr = l & 15, g0 = l >> 4, c = t & 7;
  const int id = blockIdx.x;
  const int wg = ((id & 7) << 5) + (id >> 3);
  const int b = wg >> 6, by = (wg >> 3) & 7, bx = wg & 7;
  const f16* ab = abf + ((size_t)b << 22);
  const f16* vb = vtT + ((size_t)b << 21);
  const f16 *aP[4], *bP[2];
#pragma unroll
  for (int i = 0; i < 4; ++i) {
    const int rl = i * 64 + (t >> 3);
    aP[i] = ab + (size_t)(bx * 256 + rl) * 2048 + ((c ^ (rl & 7)) << 3);
  }
#pragma unroll
  for (int i = 0; i < 2; ++i) {
    const int rl = i * 64 + (t >> 3);
    bP[i] = vb + (size_t)(by * 128 + rl) * 2048 +
            ((c ^ ((rl >> 2) & 7)) << 3);
  }
  f32x4 acc[16];
  gemm8_core<128>(aP[0], aP[1], aP[2], aP[3], bP[0], bP[1], bP[0], bP[0],
                  64, 64, 32, lds, acc);
  f16* Cb = attb + ((size_t)b << 21);
  const int col = by * 128 + wn * 32 + fr * 2;
#pragma unroll
  for (int mi = 0; mi < 8; ++mi)
#pragma unroll
    for (int q = 0; q < 4; ++q) {
      const int row = bx * 256 + wm * 128 + mi * 16 + g0 * 4 + q;
      f16x2 o = {(f16)acc[mi * 2 + 0][q], (f16)acc[mi * 2 + 1][q]};
      *(f16x2*)(Cb + (size_t)row * 1024 + col) = o;
    }
}

// ----------------- merged prep: src cast (blocks 0..4095) + W^T cast (rest)
__global__ __launch_bounds__(256) void k_prep(
    const float* __restrict__ src, const float* __restrict__ w0,
    const float* __restrict__ w1, const float* __restrict__ w2,
    f16* __restrict__ srch, f16* __restrict__ wt)
{
  const int b = blockIdx.x, t = threadIdx.x;
  if (b < 4096) {
    const size_t i = (size_t)b * 256 + t;
    const float4* p = (const float4*)src;
    float4 v0 = p[2 * i], v1 = p[2 * i + 1];
    f16x8 o;
    o[0] = (f16)v0.x; o[1] = (f16)v0.y; o[2] = (f16)v0.z; o[3] = (f16)v0.w;
    o[4] = (f16)v1.x; o[5] = (f16)v1.y; o[6] = (f16)v1.z; o[7] = (f16)v1.w;
    *(f16x8*)(srch + 8 * i) = o;
    return;
  }
  const int id = b - 4096;            // 0..767
  const int z = id >> 8, rem = id & 255;
  const int bx = rem & 15, by = rem >> 4;
  const float* in = (z == 0) ? w0 : (z == 1 ? w1 : w2);
  f16* o = wt + ((size_t)z << 20);
  __shared__ f16 tile[64][65];
  const int rr = t >> 4, c4 = (t & 15) * 4;
  const int r0 = bx * 64, c0 = by * 64;
#pragma unroll
  for (int i = 0; i < 4; ++i) {
    float4 f = *(const float4*)(in + (size_t)(r0 + rr + 16 * i) * 1024 + c0 + c4);
    tile[rr + 16 * i][c4 + 0] = (f16)f.x;
    tile[rr + 16 * i][c4 + 1] = (f16)f.y;
    tile[rr + 16 * i][c4 + 2] = (f16)f.z;
    tile[rr + 16 * i][c4 + 3] = (f16)f.w;
  }
  __syncthreads();
#pragma unroll
  for (int i = 0; i < 4; ++i) {
    const int n = c0 + rr + 16 * i;
    f16* dst = o + (size_t)n * 1024 + r0 + c4;
    dst[0] = tile[c4 + 0][rr + 16 * i];
    dst[1] = tile[c4 + 1][rr + 16 * i];
    dst[2] = tile[c4 + 2][rr + 16 * i];
    dst[3] = tile[c4 + 3][rr + 16 * i];
  }
}

// ---------- merged: softmax rows (blocks 0..8191) + V scramble-T (rest)
__global__ __launch_bounds__(256) void k_softscr(
    float* __restrict__ out, f16* __restrict__ abf,
    const f16* __restrict__ vp, f16* __restrict__ vtT)
{
  __shared__ f16 shm[64][68];
  const int t = threadIdx.x;
  if (blockIdx.x < 8192) {
    float* red = (float*)&shm[0][0];
    const size_t base = (size_t)blockIdx.x * 2048;
    const int lane = t & 63, w = t >> 6;
    f16x8 v = *(const f16x8*)(abf + base + (size_t)t * 8);
    float x[8];
#pragma unroll
    for (int j = 0; j < 8; ++j) x[j] = (float)v[j];
    float m = fmaxf(fmaxf(fmaxf(x[0], x[1]), fmaxf(x[2], x[3])),
                    fmaxf(fmaxf(x[4], x[5]), fmaxf(x[6], x[7])));
#pragma unroll
    for (int off = 1; off < 64; off <<= 1) m = fmaxf(m, __shfl_xor(m, off));
    if (lane == 0) red[w] = m;
    __syncthreads();
    m = fmaxf(fmaxf(red[0], red[1]), fmaxf(red[2], red[3]));
    float s = 0.f;
#pragma unroll
    for (int j = 0; j < 8; ++j) { x[j] = __expf(x[j] - m); s += x[j]; }
#pragma unroll
    for (int off = 1; off < 64; off <<= 1) s += __shfl_xor(s, off);
    if (lane == 0) red[4 + w] = s;
    __syncthreads();
    s = red[4] + red[5] + red[6] + red[7];
    const float inv = 1.0f / s;
#pragma unroll
    for (int j = 0; j < 8; ++j) x[j] *= inv;
    float4 o0 = {x[0], x[1], x[2], x[3]}, o1 = {x[4], x[5], x[6], x[7]};
    ((float4*)(out + base))[2 * t] = o0;
    ((float4*)(out + base))[2 * t + 1] = o1;
    f16x8 ov;
#pragma unroll
    for (int j = 0; j < 8; ++j) ov[j] = (f16)x[j];
    *(f16x8*)(abf + base + (size_t)t * 8) = ov;
    return;
  }
  const int id = blockIdx.x - 8192;           // 0..2047
  const int sx = id & 31, sy = (id >> 5) & 15, bz = id >> 9;
  const int sp0 = sx * 64, dp0 = sy * 64;
  const int d6 = dp0 >> 6;
  const int jb = (sp0 >> 7) << 6;
  const int sbase = sp0 & 127;
  const f16* srcv = vp + ((size_t)bz << 21);
  f16* dstv = vtT + ((size_t)bz << 21);
#pragma unroll
  for (int p = 0; p < 2; ++p) {
    const int u = p * 32 + (t >> 3);
    const int s = ((sbase + u) << 4) | d6;
    const int cc = (t & 7) << 3;
    f16x8 v = *(const f16x8*)(srcv + (size_t)s * 1024 + jb + cc);
    *(f16x4*)&shm[u][cc]     = f16x4{v[0], v[1], v[2], v[3]};
    *(f16x4*)&shm[u][cc + 4] = f16x4{v[4], v[5], v[6], v[7]};
  }
  __syncthreads();
#pragma unroll
  for (int p = 0; p < 2; ++p) {
    const int cc = p * 32 + (t >> 3);
    const int v0 = (t & 7) << 3;
    f16x8 o;
#pragma unroll
    for (int j = 0; j < 8; ++j) o[j] = shm[v0 + j][cc];
    *(f16x8*)(dstv + (size_t)(dp0 + cc) * 2048 + sp0 + v0) = o;
  }
}

// --------------------------------------------- fused LN1 + add + LN2
__global__ __launch_bounds__(256) void k_ln(
    const f16* __restrict__ attb, const float* __restrict__ src,
    const float* __restrict__ w1, const float* __restrict__ b1,
    const float* __restrict__ w2, const float* __restrict__ b2,
    float* __restrict__ out)
{
  const size_t base = (size_t)blockIdx.x * 1024;
  const int t = threadIdx.x, lane = t & 63, w = t >> 6;
  f16x4 a4 = ((const f16x4*)(attb + base))[t];
  float ax = (float)a4[0], ay = (float)a4[1], az = (float)a4[2], aw = (float)a4[3];
  float s = ax + ay + az + aw;
  float s2 = ax * ax + ay * ay + az * az + aw * aw;
#pragma unroll
  for (int off = 1; off < 64; off <<= 1) {
    s += __shfl_xor(s, off);
    s2 += __shfl_xor(s2, off);
  }
  __shared__ float red[16];
  if (lane == 0) { red[w] = s; red[4 + w] = s2; }
  __syncthreads();
  s = red[0] + red[1] + red[2] + red[3];
  s2 = red[4] + red[5] + red[6] + red[7];
  float mu = s * (1.0f / 1024.0f);
  float var = s2 * (1.0f / 1024.0f) - mu * mu;
  float rs = rsqrtf(var + 1e-5f);
  float4 W1 = ((const float4*)w1)[t], B1 = ((const float4*)b1)[t];
  float4 sv = ((const float4*)(src + base))[t];
  float y0 = sv.x + (ax - mu) * rs * W1.x + B1.x;
  float y1 = sv.y + (ay - mu) * rs * W1.y + B1.y;
  float y2 = sv.z + (az - mu) * rs * W1.z + B1.z;
  float y3 = sv.w + (aw - mu) * rs * W1.w + B1.w;
  s = y0 + y1 + y2 + y3;
  s2 = y0 * y0 + y1 * y1 + y2 * y2 + y3 * y3;
#pragma unroll
  for (int off = 1; off < 64; off <<= 1) {
    s += __shfl_xor(s, off);
    s2 += __shfl_xor(s2, off);
  }
  if (lane == 0) { red[8 + w] = s; red[12 + w] = s2; }
  __syncthreads();
  s = red[8] + red[9] + red[10] + red[11];
  s2 = red[12] + red[13] + red[14] + red[15];
  mu = s * (1.0f / 1024.0f);
  var = s2 * (1.0f / 1024.0f) - mu * mu;
  rs = rsqrtf(var + 1e-5f);
  float4 W2 = ((const float4*)w2)[t], B2 = ((const float4*)b2)[t];
  float4 o;
  o.x = (y0 - mu) * rs * W2.x + B2.x;
  o.y = (y1 - mu) * rs * W2.y + B2.y;
  o.z = (y2 - mu) * rs * W2.z + B2.z;
  o.w = (y3 - mu) * rs * W2.w + B2.w;
  ((float4*)(out + base))[t] = o;
}

// ---------------------------------------------------------------- launch
extern "C" void kernel_launch(void* const* d_in, const int* in_sizes, int n_in,
                              void* d_out, int out_size, void* d_ws, size_t ws_size,
                              hipStream_t stream) {
  const float* src = (const float*)d_in[0];
  const float* Wq  = (const float*)d_in[1];
  const float* Wk  = (const float*)d_in[2];
  const float* Wv  = (const float*)d_in[3];
  const float* l1w = (const float*)d_in[4];
  const float* l1b = (const float*)d_in[5];
  const float* l2w = (const float*)d_in[6];
  const float* l2b = (const float*)d_in[7];
  float* Xout = (float*)d_out;
  float* Aout = Xout + (size_t)NROWS * D_MODEL;

  // workspace layout (134 MB, non-overlapping)
  char* ws = (char*)d_ws;
  f16* srch = (f16*)ws;                       // 16 MB (8192x1024)
  f16* wt   = (f16*)(ws + (16u << 20));       //  6 MB (3072x1024, W^T)
  f16* qp   = (f16*)(ws + (22u << 20));       // 16 MB
  f16* kp   = (f16*)(ws + (38u << 20));       // 16 MB
  f16* vp   = (f16*)(ws + (54u << 20));       // 16 MB
  f16* vtT  = (f16*)(ws + (70u << 20));       // 16 MB (B,D,S scrambled-T)
  f16* abf  = (f16*)(ws + (86u << 20));       // 32 MB (B,S,S scores->a f16)
  f16* attb = (f16*)(ws + (118u << 20));      // 16 MB (B,S,D f16)

  k_prep<<<4864, 256, 0, stream>>>(src, Wq, Wk, Wv, srch, wt);
  k_qkv3<<<dim3(32, 24), 512, 0, stream>>>(srch, wt, qp, kp, vp);
  k_scores<<<256, 512, 0, stream>>>(qp, kp, abf);
  k_softscr<<<8192 + 2048, 256, 0, stream>>>(Aout, abf, vp, vtT);
  k_att<<<256, 512, 0, stream>>>(abf, vtT, attb);
  k_ln<<<NROWS, 256, 0, stream>>>(attb, src, l1w, l1b, l2w, l2b, Xout);
}

// Round 10
// 193.177 us; speedup vs baseline: 1.1251x; 1.0053x over previous
//
#include <hip/hip_runtime.h>

typedef _Float16 f16;
typedef __attribute__((ext_vector_type(2))) _Float16 f16x2;
typedef __attribute__((ext_vector_type(4))) _Float16 f16x4;
typedef __attribute__((ext_vector_type(8))) _Float16 f16x8;
typedef __attribute__((ext_vector_type(4))) float f32x4;

#define D_MODEL 1024
#define SEQ 2048
#define NBATCH 4
#define NROWS (NBATCH * SEQ)  // 8192

// ---------------------------------------------------------------- utilities
__device__ __forceinline__ void gload16(const void* g, void* l) {
  __builtin_amdgcn_global_load_lds(
      (__attribute__((address_space(1))) void*)(void*)g,
      (__attribute__((address_space(3))) void*)l, 16, 0, 0);
}

#define BARF                                   \
  do {                                         \
    asm volatile("" ::: "memory");             \
    __builtin_amdgcn_s_barrier();              \
    asm volatile("" ::: "memory");             \
  } while (0)
#define PRIO1 __builtin_amdgcn_s_setprio(1)
#define PRIO0 __builtin_amdgcn_s_setprio(0)

// ---------------------------------------------------------- 8-wave GEMM core
// (R4/R8 best-measured 2-phase core, verbatim.)
template <int BN>
__device__ __forceinline__ void gemm8_core(
    const f16* aP0, const f16* aP1, const f16* aP2, const f16* aP3,
    const f16* bP0, const f16* bP1, const f16* bP2, const f16* bP3,
    int stepA, int stepB, int NT, f16* lds, f32x4* acc)
{
  constexpr int NJ = BN / 128;           // n-frag pairs per n-half (2|1)
  constexpr int NACC = 2 * NJ;           // acc columns (4|2)
  constexpr int SLOT = 16384 + BN * 64;  // f16 units per slot
  const int t = threadIdx.x, l = t & 63;
  const int w = t >> 6, wm = w >> 2, wn = w & 3;
  const int fr = l & 15, g0 = l >> 4;

  int aof[2][4][2], bof[2][NJ][2];
#pragma unroll
  for (int mh = 0; mh < 2; ++mh)
#pragma unroll
    for (int mi = 0; mi < 4; ++mi)
#pragma unroll
      for (int kh = 0; kh < 2; ++kh) {
        const int ra = wm * 128 + mh * 64 + mi * 16 + fr;
        aof[mh][mi][kh] = ra * 64 + (((g0 + kh * 4) ^ (ra & 7)) << 3);
      }
#pragma unroll
  for (int nh = 0; nh < 2; ++nh)
#pragma unroll
    for (int j = 0; j < NJ; ++j)
#pragma unroll
      for (int kh = 0; kh < 2; ++kh) {
        const int rb = (BN == 256) ? (wn * 64 + fr * 4 + nh * 2 + j)
                                   : (wn * 32 + fr * 2 + nh);
        bof[nh][j][kh] = rb * 64 + (((g0 + kh * 4) ^ ((rb >> 2) & 7)) << 3);
      }
#pragma unroll
  for (int i = 0; i < 8 * NACC; ++i) acc[i] = f32x4{0.f, 0.f, 0.f, 0.f};

  f16x8 fa[4][2];
  f16x8 fb[2][NJ][2];

#define STAGE_A(SL)                                  \
  {                                                  \
    f16* d = lds + (SL) * SLOT + t * 8;              \
    gload16(aP0, d);                                 \
    gload16(aP1, d + 4096);                          \
    gload16(aP2, d + 8192);                          \
    gload16(aP3, d + 12288);                         \
  }
#define STAGE_B(SL)                                  \
  {                                                  \
    f16* d = lds + (SL) * SLOT + 16384 + t * 8;      \
    gload16(bP0, d);                                 \
    gload16(bP1, d + 4096);                          \
    if constexpr (BN == 256) {                       \
      gload16(bP2, d + 8192);                        \
      gload16(bP3, d + 12288);                       \
    }                                                \
  }
#define ADVA { aP0 += stepA; aP1 += stepA; aP2 += stepA; aP3 += stepA; }
#define ADVB                                         \
  {                                                  \
    bP0 += stepB; bP1 += stepB;                      \
    if constexpr (BN == 256) { bP2 += stepB; bP3 += stepB; } \
  }
#define VMC                                                        \
  if constexpr (BN == 256) {                                       \
    asm volatile("s_waitcnt vmcnt(4)" ::: "memory");               \
  } else {                                                         \
    asm volatile("s_waitcnt vmcnt(2)" ::: "memory");               \
  }
#define LOAD_A(MH)                                   \
  _Pragma("unroll") for (int mi = 0; mi < 4; ++mi)   \
  _Pragma("unroll") for (int kh = 0; kh < 2; ++kh)   \
      fa[mi][kh] = *(const f16x8*)(LA + aof[MH][mi][kh]);
#define LOAD_B(NH)                                   \
  _Pragma("unroll") for (int j = 0; j < NJ; ++j)     \
  _Pragma("unroll") for (int kh = 0; kh < 2; ++kh)   \
      fb[NH][j][kh] = *(const f16x8*)(LBp + bof[NH][j][kh]);
#define MFMA_BLK(MH, NH)                                                    \
  _Pragma("unroll") for (int mi = 0; mi < 4; ++mi)                          \
  _Pragma("unroll") for (int j = 0; j < NJ; ++j)                            \
  _Pragma("unroll") for (int kh = 0; kh < 2; ++kh)                          \
      acc[((MH)*4 + mi) * NACC + (NH)*NJ + j] =                             \
          __builtin_amdgcn_mfma_f32_16x16x32_f16(                           \
              fa[mi][kh], fb[NH][j][kh],                                    \
              acc[((MH)*4 + mi) * NACC + (NH)*NJ + j], 0, 0, 0);

  (void)bP2; (void)bP3;
  STAGE_A(0); ADVA;
  STAGE_B(0); ADVB;
  STAGE_B(1); ADVB;
  VMC;
  BARF;

  for (int kt = 0; kt < NT; ++kt) {
    const int sl = kt & 1;
    const f16* LA = lds + sl * SLOT;
    const f16* LBp = LA + 16384;
    STAGE_A(sl ^ 1);
    if (kt + 2 < NT) ADVA;
    LOAD_A(0); LOAD_B(0); LOAD_B(1);
    PRIO1; MFMA_BLK(0, 0); MFMA_BLK(0, 1); PRIO0;
    BARF;
    LOAD_A(1);
    STAGE_B(sl);
    if (kt + 3 < NT) ADVB;
    VMC;
    PRIO1; MFMA_BLK(1, 0); MFMA_BLK(1, 1); PRIO0;
    BARF;
  }
#undef STAGE_A
#undef STAGE_B
#undef ADVA
#undef ADVB
#undef VMC
#undef LOAD_A
#undef LOAD_B
#undef MFMA_BLK
}

// ------------------------------------------- GEMM1: QKV, BN=128, grid 32x24
__global__ __launch_bounds__(512, 2) void k_qkv3(
    const f16* __restrict__ srch, const f16* __restrict__ wt,
    f16* __restrict__ qp, f16* __restrict__ kp, f16* __restrict__ vp)
{
  __shared__ f16 lds[2 * (16384 + 128 * 64)];
  const int t = threadIdx.x, l = t & 63;
  const int w = t >> 6, wm = w >> 2, wn = w & 3;
  const int fr = l & 15, g0 = l >> 4, c = t & 7;
  const int z = blockIdx.y >> 3, cb = blockIdx.y & 7;
  const f16 *aP[4], *bP[2];
#pragma unroll
  for (int i = 0; i < 4; ++i) {
    const int rl = i * 64 + (t >> 3);
    aP[i] = srch + (size_t)(blockIdx.x * 256 + rl) * 1024 + ((c ^ (rl & 7)) << 3);
  }
#pragma unroll
  for (int i = 0; i < 2; ++i) {
    const int rl = i * 64 + (t >> 3);
    bP[i] = wt + ((size_t)z << 20) + (size_t)(cb * 128 + rl) * 1024 +
            ((c ^ ((rl >> 2) & 7)) << 3);
  }
  f32x4 acc[16];
  gemm8_core<128>(aP[0], aP[1], aP[2], aP[3], bP[0], bP[1], bP[0], bP[0],
                  64, 64, 16, lds, acc);
  f16* dst = (z == 0) ? qp : (z == 1 ? kp : vp);
  const int col = cb * 128 + wn * 32 + fr * 2;
#pragma unroll
  for (int mi = 0; mi < 8; ++mi)
#pragma unroll
    for (int q = 0; q < 4; ++q) {
      const int row = blockIdx.x * 256 + wm * 128 + mi * 16 + g0 * 4 + q;
      f16x2 o = {(f16)acc[mi * 2 + 0][q], (f16)acc[mi * 2 + 1][q]};
      *(f16x2*)(dst + (size_t)row * 1024 + col) = o;
    }
}

// ------------ GEMM2: e = exp(Qt*Kt^T/32) f16 + per-row sum atomics
__global__ __launch_bounds__(512, 2) void k_scores(
    const f16* __restrict__ qp, const f16* __restrict__ kp,
    f16* __restrict__ abf, float* __restrict__ sums)
{
  __shared__ f16 lds[2 * (16384 + 256 * 64)];
  const int t = threadIdx.x, l = t & 63;
  const int w = t >> 6, wm = w >> 2, wn = w & 3;
  const int fr = l & 15, g0 = l >> 4, c = t & 7;
  const int id = blockIdx.x;
  const int wg = ((id & 7) << 5) + (id >> 3);
  const int b = wg >> 6, by = (wg >> 3) & 7, bx = wg & 7;
  const f16* qb = qp + ((size_t)b << 21);
  const f16* kb = kp + ((size_t)b << 21);
  const f16 *aP[4], *bP[4];
#pragma unroll
  for (int i = 0; i < 4; ++i) {
    const int rl = i * 64 + (t >> 3);
    const int spA = bx * 256 + rl;
    aP[i] = qb + (size_t)((spA & 127) << 4) * 1024 + ((spA >> 7) << 6) +
            ((c ^ (rl & 7)) << 3);
    const int spB = by * 256 + rl;
    bP[i] = kb + (size_t)((spB & 127) << 4) * 1024 + ((spB >> 7) << 6) +
            ((c ^ ((rl >> 2) & 7)) << 3);
  }
  f32x4 acc[32];
  gemm8_core<256>(aP[0], aP[1], aP[2], aP[3], bP[0], bP[1], bP[2], bP[3],
                  1024, 1024, 16, lds, acc);
  f16* Cb = abf + ((size_t)b << 22);
  float* sums_b = sums + (b << 11);
  const int col = by * 256 + wn * 64 + fr * 4;
#pragma unroll
  for (int mi = 0; mi < 8; ++mi)
#pragma unroll
    for (int q = 0; q < 4; ++q) {
      const int row = bx * 256 + wm * 128 + mi * 16 + g0 * 4 + q;
      float e0 = __expf(acc[mi * 4 + 0][q] * 0.03125f);
      float e1 = __expf(acc[mi * 4 + 1][q] * 0.03125f);
      float e2 = __expf(acc[mi * 4 + 2][q] * 0.03125f);
      float e3 = __expf(acc[mi * 4 + 3][q] * 0.03125f);
      f16x4 o = {(f16)e0, (f16)e1, (f16)e2, (f16)e3};
      *(f16x4*)(Cb + (size_t)row * 2048 + col) = o;
      float p = e0 + e1 + e2 + e3;
      p += __shfl_xor(p, 1);
      p += __shfl_xor(p, 2);
      p += __shfl_xor(p, 4);
      p += __shfl_xor(p, 8);
      if (fr == 0) atomicAdd(&sums_b[row], p);
    }
}

// -------- GEMM3: att = (e @ Vt)/s, f16 out; also writes a = e/s (f32 slice)
__global__ __launch_bounds__(512, 2) void k_att(
    const f16* __restrict__ abf, const f16* __restrict__ vtT,
    const float* __restrict__ sums, f16* __restrict__ attb,
    float* __restrict__ Aout)
{
  __shared__ f16 lds[2 * (16384 + 128 * 64)];
  const int t = threadIdx.x, l = t & 63;
  const int w = t >> 6, wm = w >> 2, wn = w & 3;
  const int fr = l & 15, g0 = l >> 4, c = t & 7;
  const int id = blockIdx.x;
  const int wg = ((id & 7) << 5) + (id >> 3);
  const int b = wg >> 6, by = (wg >> 3) & 7, bx = wg & 7;
  const f16* ab = abf + ((size_t)b << 22);
  const f16* vb = vtT + ((size_t)b << 21);
  const f16 *aP[4], *bP[2];
#pragma unroll
  for (int i = 0; i < 4; ++i) {
    const int rl = i * 64 + (t >> 3);
    aP[i] = ab + (size_t)(bx * 256 + rl) * 2048 + ((c ^ (rl & 7)) << 3);
  }
#pragma unroll
  for (int i = 0; i < 2; ++i) {
    const int rl = i * 64 + (t >> 3);
    bP[i] = vb + (size_t)(by * 128 + rl) * 2048 +
            ((c ^ ((rl >> 2) & 7)) << 3);
  }
  f32x4 acc[16];
  gemm8_core<128>(aP[0], aP[1], aP[2], aP[3], bP[0], bP[1], bP[0], bP[0],
                  64, 64, 32, lds, acc);
  const float* sums_b = sums + (b << 11);
  f16* Cb = attb + ((size_t)b << 21);
  const int col = by * 128 + wn * 32 + fr * 2;
#pragma unroll
  for (int mi = 0; mi < 8; ++mi)
#pragma unroll
    for (int q = 0; q < 4; ++q) {
      const int row = bx * 256 + wm * 128 + mi * 16 + g0 * 4 + q;
      const float is = 1.0f / sums_b[row];
      f16x2 o = {(f16)(acc[mi * 2 + 0][q] * is), (f16)(acc[mi * 2 + 1][q] * is)};
      *(f16x2*)(Cb + (size_t)row * 1024 + col) = o;
    }
  // ---- a-write: a[rows bx*256.., cols by*256..] = e * (1/s)
  float* Ab = Aout + ((size_t)b << 22);
#pragma unroll
  for (int i = 0; i < 16; ++i) {
    const int idx = t + i * 512;          // 0..8191
    const int rr = idx >> 5;              // 0..255
    const int cg = (idx & 31) * 8;        // 0..248
    const int grow = bx * 256 + rr;
    const float is = 1.0f / sums_b[grow];
    f16x8 ev = *(const f16x8*)(ab + (size_t)grow * 2048 + by * 256 + cg);
    float4 o0 = {(float)ev[0] * is, (float)ev[1] * is,
                 (float)ev[2] * is, (float)ev[3] * is};
    float4 o1 = {(float)ev[4] * is, (float)ev[5] * is,
                 (float)ev[6] * is, (float)ev[7] * is};
    float* dst = Ab + (size_t)grow * 2048 + by * 256 + cg;
    *(float4*)dst = o0;
    *(float4*)(dst + 4) = o1;
  }
}

// ----------------- merged prep: src cast (blocks 0..4095) + W^T cast (rest)
__global__ __launch_bounds__(256) void k_prep(
    const float* __restrict__ src, const float* __restrict__ w0,
    const float* __restrict__ w1, const float* __restrict__ w2,
    f16* __restrict__ srch, f16* __restrict__ wt)
{
  const int b = blockIdx.x, t = threadIdx.x;
  if (b < 4096) {
    const size_t i = (size_t)b * 256 + t;
    const float4* p = (const float4*)src;
    float4 v0 = p[2 * i], v1 = p[2 * i + 1];
    f16x8 o;
    o[0] = (f16)v0.x; o[1] = (f16)v0.y; o[2] = (f16)v0.z; o[3] = (f16)v0.w;
    o[4] = (f16)v1.x; o[5] = (f16)v1.y; o[6] = (f16)v1.z; o[7] = (f16)v1.w;
    *(f16x8*)(srch + 8 * i) = o;
    return;
  }
  const int id = b - 4096;            // 0..767
  const int z = id >> 8, rem = id & 255;
  const int bx = rem & 15, by = rem >> 4;
  const float* in = (z == 0) ? w0 : (z == 1 ? w1 : w2);
  f16* o = wt + ((size_t)z << 20);
  __shared__ f16 tile[64][65];
  const int rr = t >> 4, c4 = (t & 15) * 4;
  const int r0 = bx * 64, c0 = by * 64;
#pragma unroll
  for (int i = 0; i < 4; ++i) {
    float4 f = *(const float4*)(in + (size_t)(r0 + rr + 16 * i) * 1024 + c0 + c4);
    tile[rr + 16 * i][c4 + 0] = (f16)f.x;
    tile[rr + 16 * i][c4 + 1] = (f16)f.y;
    tile[rr + 16 * i][c4 + 2] = (f16)f.z;
    tile[rr + 16 * i][c4 + 3] = (f16)f.w;
  }
  __syncthreads();
#pragma unroll
  for (int i = 0; i < 4; ++i) {
    const int n = c0 + rr + 16 * i;
    f16* dst = o + (size_t)n * 1024 + r0 + c4;
    dst[0] = tile[c4 + 0][rr + 16 * i];
    dst[1] = tile[c4 + 1][rr + 16 * i];
    dst[2] = tile[c4 + 2][rr + 16 * i];
    dst[3] = tile[c4 + 3][rr + 16 * i];
  }
}

// ---------- scramble-transpose of V (blocks 0..2047) + zero sums (block 2048)
__global__ __launch_bounds__(256) void k_scrT(const f16* __restrict__ vp,
                                              f16* __restrict__ vtT,
                                              float* __restrict__ sums)
{
  const int t = threadIdx.x;
  if (blockIdx.x == 2048) {
    f32x4 z = {0.f, 0.f, 0.f, 0.f};
#pragma unroll
    for (int i = 0; i < 8; ++i)
      *(f32x4*)(sums + (size_t)(t * 8 + i * 2048) * 4 / 4 + 0) = z,
      ((f32x4*)sums)[t + i * 256] = z;
    return;
  }
  __shared__ f16 tile[64][68];
  const int id = blockIdx.x;
  const int sx = id & 31, sy = (id >> 5) & 15, bz = id >> 9;
  const int sp0 = sx * 64, dp0 = sy * 64;
  const int d6 = dp0 >> 6;
  const int jb = (sp0 >> 7) << 6;
  const int sbase = sp0 & 127;
  const f16* srcv = vp + ((size_t)bz << 21);
  f16* dstv = vtT + ((size_t)bz << 21);
#pragma unroll
  for (int p = 0; p < 2; ++p) {
    const int u = p * 32 + (t >> 3);
    const int s = ((sbase + u) << 4) | d6;
    const int cc = (t & 7) << 3;
    f16x8 v = *(const f16x8*)(srcv + (size_t)s * 1024 + jb + cc);
    *(f16x4*)&tile[u][cc]     = f16x4{v[0], v[1], v[2], v[3]};
    *(f16x4*)&tile[u][cc + 4] = f16x4{v[4], v[5], v[6], v[7]};
  }
  __syncthreads();
#pragma unroll
  for (int p = 0; p < 2; ++p) {
    const int cc = p * 32 + (t >> 3);
    const int v0 = (t & 7) << 3;
    f16x8 o;
#pragma unroll
    for (int j = 0; j < 8; ++j) o[j] = tile[v0 + j][cc];
    *(f16x8*)(dstv + (size_t)(dp0 + cc) * 2048 + sp0 + v0) = o;
  }
}

// --------------------------------------------- fused LN1 + add + LN2
__global__ __launch_bounds__(256) void k_ln(
    const f16* __restrict__ attb, const float* __restrict__ src,
    const float* __restrict__ w1, const float* __restrict__ b1,
    const float* __restrict__ w2, const float* __restrict__ b2,
    float* __restrict__ out)
{
  const size_t base = (size_t)blockIdx.x * 1024;
  const int t = threadIdx.x, lane = t & 63, w = t >> 6;
  f16x4 a4 = ((const f16x4*)(attb + base))[t];
  float ax = (float)a4[0], ay = (float)a4[1], az = (float)a4[2], aw = (float)a4[3];
  float s = ax + ay + az + aw;
  float s2 = ax * ax + ay * ay + az * az + aw * aw;
#pragma unroll
  for (int off = 1; off < 64; off <<= 1) {
    s += __shfl_xor(s, off);
    s2 += __shfl_xor(s2, off);
  }
  __shared__ float red[16];
  if (lane == 0) { red[w] = s; red[4 + w] = s2; }
  __syncthreads();
  s = red[0] + red[1] + red[2] + red[3];
  s2 = red[4] + red[5] + red[6] + red[7];
  float mu = s * (1.0f / 1024.0f);
  float var = s2 * (1.0f / 1024.0f) - mu * mu;
  float rs = rsqrtf(var + 1e-5f);
  float4 W1 = ((const float4*)w1)[t], B1 = ((const float4*)b1)[t];
  float4 sv = ((const float4*)(src + base))[t];
  float y0 = sv.x + (ax - mu) * rs * W1.x + B1.x;
  float y1 = sv.y + (ay - mu) * rs * W1.y + B1.y;
  float y2 = sv.z + (az - mu) * rs * W1.z + B1.z;
  float y3 = sv.w + (aw - mu) * rs * W1.w + B1.w;
  s = y0 + y1 + y2 + y3;
  s2 = y0 * y0 + y1 * y1 + y2 * y2 + y3 * y3;
#pragma unroll
  for (int off = 1; off < 64; off <<= 1) {
    s += __shfl_xor(s, off);
    s2 += __shfl_xor(s2, off);
  }
  if (lane == 0) { red[8 + w] = s; red[12 + w] = s2; }
  __syncthreads();
  s = red[8] + red[9] + red[10] + red[11];
  s2 = red[12] + red[13] + red[14] + red[15];
  mu = s * (1.0f / 1024.0f);
  var = s2 * (1.0f / 1024.0f) - mu * mu;
  rs = rsqrtf(var + 1e-5f);
  float4 W2 = ((const float4*)w2)[t], B2 = ((const float4*)b2)[t];
  float4 o;
  o.x = (y0 - mu) * rs * W2.x + B2.x;
  o.y = (y1 - mu) * rs * W2.y + B2.y;
  o.z = (y2 - mu) * rs * W2.z + B2.z;
  o.w = (y3 - mu) * rs * W2.w + B2.w;
  ((float4*)(out + base))[t] = o;
}

// ---------------------------------------------------------------- launch
extern "C" void kernel_launch(void* const* d_in, const int* in_sizes, int n_in,
                              void* d_out, int out_size, void* d_ws, size_t ws_size,
                              hipStream_t stream) {
  const float* src = (const float*)d_in[0];
  const float* Wq  = (const float*)d_in[1];
  const float* Wk  = (const float*)d_in[2];
  const float* Wv  = (const float*)d_in[3];
  const float* l1w = (const float*)d_in[4];
  const float* l1b = (const float*)d_in[5];
  const float* l2w = (const float*)d_in[6];
  const float* l2b = (const float*)d_in[7];
  float* Xout = (float*)d_out;
  float* Aout = Xout + (size_t)NROWS * D_MODEL;

  // workspace layout (134 MB)
  char* ws = (char*)d_ws;
  f16* srch = (f16*)ws;                       // 16 MB (8192x1024); dead after qkv
  float* sums = (float*)ws;                   // 32 KB (overlays dead srch)
  f16* wt   = (f16*)(ws + (16u << 20));       //  6 MB (3072x1024, W^T)
  f16* qp   = (f16*)(ws + (22u << 20));       // 16 MB
  f16* kp   = (f16*)(ws + (38u << 20));       // 16 MB
  f16* vp   = (f16*)(ws + (54u << 20));       // 16 MB
  f16* vtT  = (f16*)(ws + (70u << 20));       // 16 MB (B,D,S scrambled-T)
  f16* abf  = (f16*)(ws + (86u << 20));       // 32 MB (B,S,S e f16)
  f16* attb = (f16*)(ws + (118u << 20));      // 16 MB (B,S,D f16)

  k_prep<<<4864, 256, 0, stream>>>(src, Wq, Wk, Wv, srch, wt);
  k_qkv3<<<dim3(32, 24), 512, 0, stream>>>(srch, wt, qp, kp, vp);
  k_scrT<<<2049, 256, 0, stream>>>(vp, vtT, sums);   // + zeroes sums
  k_scores<<<256, 512, 0, stream>>>(qp, kp, abf, sums);
  k_att<<<256, 512, 0, stream>>>(abf, vtT, sums, attb, Aout);
  k_ln<<<NROWS, 256, 0, stream>>>(attb, src, l1w, l1b, l2w, l2b, Xout);
}

// Round 11
// 185.238 us; speedup vs baseline: 1.1733x; 1.0429x over previous
//
#include <hip/hip_runtime.h>

typedef _Float16 f16;
typedef __attribute__((ext_vector_type(2))) _Float16 f16x2;
typedef __attribute__((ext_vector_type(4))) _Float16 f16x4;
typedef __attribute__((ext_vector_type(8))) _Float16 f16x8;
typedef __attribute__((ext_vector_type(4))) float f32x4;

#define D_MODEL 1024
#define SEQ 2048
#define NBATCH 4
#define NROWS (NBATCH * SEQ)  // 8192

// ---------------------------------------------------------------- utilities
__device__ __forceinline__ void gload16(const void* g, void* l) {
  __builtin_amdgcn_global_load_lds(
      (__attribute__((address_space(1))) void*)(void*)g,
      (__attribute__((address_space(3))) void*)l, 16, 0, 0);
}

#define BARF                                   \
  do {                                         \
    asm volatile("" ::: "memory");             \
    __builtin_amdgcn_s_barrier();              \
    asm volatile("" ::: "memory");             \
  } while (0)
#define PRIO1 __builtin_amdgcn_s_setprio(1)
#define PRIO0 __builtin_amdgcn_s_setprio(0)

// ---------------------------------------------------------- 8-wave GEMM core
// (R4/R8 best-measured 2-phase core, verbatim.)
template <int BN>
__device__ __forceinline__ void gemm8_core(
    const f16* aP0, const f16* aP1, const f16* aP2, const f16* aP3,
    const f16* bP0, const f16* bP1, const f16* bP2, const f16* bP3,
    int stepA, int stepB, int NT, f16* lds, f32x4* acc)
{
  constexpr int NJ = BN / 128;           // n-frag pairs per n-half (2|1)
  constexpr int NACC = 2 * NJ;           // acc columns (4|2)
  constexpr int SLOT = 16384 + BN * 64;  // f16 units per slot
  const int t = threadIdx.x, l = t & 63;
  const int w = t >> 6, wm = w >> 2, wn = w & 3;
  const int fr = l & 15, g0 = l >> 4;

  int aof[2][4][2], bof[2][NJ][2];
#pragma unroll
  for (int mh = 0; mh < 2; ++mh)
#pragma unroll
    for (int mi = 0; mi < 4; ++mi)
#pragma unroll
      for (int kh = 0; kh < 2; ++kh) {
        const int ra = wm * 128 + mh * 64 + mi * 16 + fr;
        aof[mh][mi][kh] = ra * 64 + (((g0 + kh * 4) ^ (ra & 7)) << 3);
      }
#pragma unroll
  for (int nh = 0; nh < 2; ++nh)
#pragma unroll
    for (int j = 0; j < NJ; ++j)
#pragma unroll
      for (int kh = 0; kh < 2; ++kh) {
        const int rb = (BN == 256) ? (wn * 64 + fr * 4 + nh * 2 + j)
                                   : (wn * 32 + fr * 2 + nh);
        bof[nh][j][kh] = rb * 64 + (((g0 + kh * 4) ^ ((rb >> 2) & 7)) << 3);
      }
#pragma unroll
  for (int i = 0; i < 8 * NACC; ++i) acc[i] = f32x4{0.f, 0.f, 0.f, 0.f};

  f16x8 fa[4][2];
  f16x8 fb[2][NJ][2];

#define STAGE_A(SL)                                  \
  {                                                  \
    f16* d = lds + (SL) * SLOT + t * 8;              \
    gload16(aP0, d);                                 \
    gload16(aP1, d + 4096);                          \
    gload16(aP2, d + 8192);                          \
    gload16(aP3, d + 12288);                         \
  }
#define STAGE_B(SL)                                  \
  {                                                  \
    f16* d = lds + (SL) * SLOT + 16384 + t * 8;      \
    gload16(bP0, d);                                 \
    gload16(bP1, d + 4096);                          \
    if constexpr (BN == 256) {                       \
      gload16(bP2, d + 8192);                        \
      gload16(bP3, d + 12288);                       \
    }                                                \
  }
#define ADVA { aP0 += stepA; aP1 += stepA; aP2 += stepA; aP3 += stepA; }
#define ADVB                                         \
  {                                                  \
    bP0 += stepB; bP1 += stepB;                      \
    if constexpr (BN == 256) { bP2 += stepB; bP3 += stepB; } \
  }
#define VMC                                                        \
  if constexpr (BN == 256) {                                       \
    asm volatile("s_waitcnt vmcnt(4)" ::: "memory");               \
  } else {                                                         \
    asm volatile("s_waitcnt vmcnt(2)" ::: "memory");               \
  }
#define LOAD_A(MH)                                   \
  _Pragma("unroll") for (int mi = 0; mi < 4; ++mi)   \
  _Pragma("unroll") for (int kh = 0; kh < 2; ++kh)   \
      fa[mi][kh] = *(const f16x8*)(LA + aof[MH][mi][kh]);
#define LOAD_B(NH)                                   \
  _Pragma("unroll") for (int j = 0; j < NJ; ++j)     \
  _Pragma("unroll") for (int kh = 0; kh < 2; ++kh)   \
      fb[NH][j][kh] = *(const f16x8*)(LBp + bof[NH][j][kh]);
#define MFMA_BLK(MH, NH)                                                    \
  _Pragma("unroll") for (int mi = 0; mi < 4; ++mi)                          \
  _Pragma("unroll") for (int j = 0; j < NJ; ++j)                            \
  _Pragma("unroll") for (int kh = 0; kh < 2; ++kh)                          \
      acc[((MH)*4 + mi) * NACC + (NH)*NJ + j] =                             \
          __builtin_amdgcn_mfma_f32_16x16x32_f16(                           \
              fa[mi][kh], fb[NH][j][kh],                                    \
              acc[((MH)*4 + mi) * NACC + (NH)*NJ + j], 0, 0, 0);

  (void)bP2; (void)bP3;
  STAGE_A(0); ADVA;
  STAGE_B(0); ADVB;
  STAGE_B(1); ADVB;
  VMC;
  BARF;

  for (int kt = 0; kt < NT; ++kt) {
    const int sl = kt & 1;
    const f16* LA = lds + sl * SLOT;
    const f16* LBp = LA + 16384;
    STAGE_A(sl ^ 1);
    if (kt + 2 < NT) ADVA;
    LOAD_A(0); LOAD_B(0); LOAD_B(1);
    PRIO1; MFMA_BLK(0, 0); MFMA_BLK(0, 1); PRIO0;
    BARF;
    LOAD_A(1);
    STAGE_B(sl);
    if (kt + 3 < NT) ADVB;
    VMC;
    PRIO1; MFMA_BLK(1, 0); MFMA_BLK(1, 1); PRIO0;
    BARF;
  }
#undef STAGE_A
#undef STAGE_B
#undef ADVA
#undef ADVB
#undef VMC
#undef LOAD_A
#undef LOAD_B
#undef MFMA_BLK
}

// ------------------------------------------- GEMM1: QKV, BN=128, grid 32x24
__global__ __launch_bounds__(512, 2) void k_qkv3(
    const f16* __restrict__ srch, const f16* __restrict__ wt,
    f16* __restrict__ qp, f16* __restrict__ kp, f16* __restrict__ vp)
{
  __shared__ f16 lds[2 * (16384 + 128 * 64)];
  const int t = threadIdx.x, l = t & 63;
  const int w = t >> 6, wm = w >> 2, wn = w & 3;
  const int fr = l & 15, g0 = l >> 4, c = t & 7;
  const int z = blockIdx.y >> 3, cb = blockIdx.y & 7;
  const f16 *aP[4], *bP[2];
#pragma unroll
  for (int i = 0; i < 4; ++i) {
    const int rl = i * 64 + (t >> 3);
    aP[i] = srch + (size_t)(blockIdx.x * 256 + rl) * 1024 + ((c ^ (rl & 7)) << 3);
  }
#pragma unroll
  for (int i = 0; i < 2; ++i) {
    const int rl = i * 64 + (t >> 3);
    bP[i] = wt + ((size_t)z << 20) + (size_t)(cb * 128 + rl) * 1024 +
            ((c ^ ((rl >> 2) & 7)) << 3);
  }
  f32x4 acc[16];
  gemm8_core<128>(aP[0], aP[1], aP[2], aP[3], bP[0], bP[1], bP[0], bP[0],
                  64, 64, 16, lds, acc);
  f16* dst = (z == 0) ? qp : (z == 1 ? kp : vp);
  const int col = cb * 128 + wn * 32 + fr * 2;
#pragma unroll
  for (int mi = 0; mi < 8; ++mi)
#pragma unroll
    for (int q = 0; q < 4; ++q) {
      const int row = blockIdx.x * 256 + wm * 128 + mi * 16 + g0 * 4 + q;
      f16x2 o = {(f16)acc[mi * 2 + 0][q], (f16)acc[mi * 2 + 1][q]};
      *(f16x2*)(dst + (size_t)row * 1024 + col) = o;
    }
}

// ------------ GEMM2: e = exp(Qt*Kt^T/32) f16 + per-row sum atomics
__global__ __launch_bounds__(512, 2) void k_scores(
    const f16* __restrict__ qp, const f16* __restrict__ kp,
    f16* __restrict__ abf, float* __restrict__ sums)
{
  __shared__ f16 lds[2 * (16384 + 256 * 64)];
  const int t = threadIdx.x, l = t & 63;
  const int w = t >> 6, wm = w >> 2, wn = w & 3;
  const int fr = l & 15, g0 = l >> 4, c = t & 7;
  const int id = blockIdx.x;
  const int wg = ((id & 7) << 5) + (id >> 3);
  const int b = wg >> 6, by = (wg >> 3) & 7, bx = wg & 7;
  const f16* qb = qp + ((size_t)b << 21);
  const f16* kb = kp + ((size_t)b << 21);
  const f16 *aP[4], *bP[4];
#pragma unroll
  for (int i = 0; i < 4; ++i) {
    const int rl = i * 64 + (t >> 3);
    const int spA = bx * 256 + rl;
    aP[i] = qb + (size_t)((spA & 127) << 4) * 1024 + ((spA >> 7) << 6) +
            ((c ^ (rl & 7)) << 3);
    const int spB = by * 256 + rl;
    bP[i] = kb + (size_t)((spB & 127) << 4) * 1024 + ((spB >> 7) << 6) +
            ((c ^ ((rl >> 2) & 7)) << 3);
  }
  f32x4 acc[32];
  gemm8_core<256>(aP[0], aP[1], aP[2], aP[3], bP[0], bP[1], bP[2], bP[3],
                  1024, 1024, 16, lds, acc);
  f16* Cb = abf + ((size_t)b << 22);
  float* sums_b = sums + (b << 11);
  const int col = by * 256 + wn * 64 + fr * 4;
#pragma unroll
  for (int mi = 0; mi < 8; ++mi)
#pragma unroll
    for (int q = 0; q < 4; ++q) {
      const int row = bx * 256 + wm * 128 + mi * 16 + g0 * 4 + q;
      float e0 = __expf(acc[mi * 4 + 0][q] * 0.03125f);
      float e1 = __expf(acc[mi * 4 + 1][q] * 0.03125f);
      float e2 = __expf(acc[mi * 4 + 2][q] * 0.03125f);
      float e3 = __expf(acc[mi * 4 + 3][q] * 0.03125f);
      f16x4 o = {(f16)e0, (f16)e1, (f16)e2, (f16)e3};
      *(f16x4*)(Cb + (size_t)row * 2048 + col) = o;
      float p = e0 + e1 + e2 + e3;
      p += __shfl_xor(p, 1);
      p += __shfl_xor(p, 2);
      p += __shfl_xor(p, 4);
      p += __shfl_xor(p, 8);
      if (fr == 0) atomicAdd(&sums_b[row], p);
    }
}

// -------- GEMM3: att = (e @ Vt)/s f16; a = e/s (f32) written IN-LOOP from
// the staged A fragments (block (b,bx,by) owns k-slice [by*256,by*256+256),
// i.e. K-steps kt>>2 == by; wn==0 waves write; exact partition of a).
__global__ __launch_bounds__(512, 2) void k_att(
    const f16* __restrict__ abf, const f16* __restrict__ vtT,
    const float* __restrict__ sums, f16* __restrict__ attb,
    float* __restrict__ Aout)
{
  __shared__ f16 lds[2 * (16384 + 128 * 64)];
  const int t = threadIdx.x, l = t & 63;
  const int w = t >> 6, wm = w >> 2, wn = w & 3;
  const int fr = l & 15, g0 = l >> 4, c = t & 7;
  const int id = blockIdx.x;
  const int wg = ((id & 7) << 5) + (id >> 3);
  const int b = wg >> 6, by = (wg >> 3) & 7, bx = wg & 7;
  const f16* ab = abf + ((size_t)b << 22);
  const f16* vb = vtT + ((size_t)b << 21);
  const float* sums_b = sums + (b << 11);
  float* Ab = Aout + ((size_t)b << 22);

  const f16 *aP0, *aP1, *aP2, *aP3, *bP0, *bP1;
  {
    const int rl0 = (t >> 3), rl1 = 64 + rl0, rl2 = 128 + rl0, rl3 = 192 + rl0;
    aP0 = ab + (size_t)(bx * 256 + rl0) * 2048 + ((c ^ (rl0 & 7)) << 3);
    aP1 = ab + (size_t)(bx * 256 + rl1) * 2048 + ((c ^ (rl1 & 7)) << 3);
    aP2 = ab + (size_t)(bx * 256 + rl2) * 2048 + ((c ^ (rl2 & 7)) << 3);
    aP3 = ab + (size_t)(bx * 256 + rl3) * 2048 + ((c ^ (rl3 & 7)) << 3);
    bP0 = vb + (size_t)(by * 128 + rl0) * 2048 + ((c ^ ((rl0 >> 2) & 7)) << 3);
    bP1 = vb + (size_t)(by * 128 + rl1) * 2048 + ((c ^ ((rl1 >> 2) & 7)) << 3);
  }

  // fragment LDS offsets (BN=128 variant of gemm8_core)
  int aof[2][4][2], bof[2][2];
#pragma unroll
  for (int mh = 0; mh < 2; ++mh)
#pragma unroll
    for (int mi = 0; mi < 4; ++mi)
#pragma unroll
      for (int kh = 0; kh < 2; ++kh) {
        const int ra = wm * 128 + mh * 64 + mi * 16 + fr;
        aof[mh][mi][kh] = ra * 64 + (((g0 + kh * 4) ^ (ra & 7)) << 3);
      }
#pragma unroll
  for (int nh = 0; nh < 2; ++nh)
#pragma unroll
    for (int kh = 0; kh < 2; ++kh) {
      const int rb = wn * 32 + fr * 2 + nh;
      bof[nh][kh] = rb * 64 + (((g0 + kh * 4) ^ ((rb >> 2) & 7)) << 3);
    }
  // preload 1/s for this lane's A-fragment rows
  float is8[2][4];
#pragma unroll
  for (int mh = 0; mh < 2; ++mh)
#pragma unroll
    for (int mi = 0; mi < 4; ++mi)
      is8[mh][mi] = 1.0f / sums_b[bx * 256 + wm * 128 + mh * 64 + mi * 16 + fr];

  f32x4 acc[16];
#pragma unroll
  for (int i = 0; i < 16; ++i) acc[i] = f32x4{0.f, 0.f, 0.f, 0.f};
  f16x8 fa[4][2], fb[2][2];
  constexpr int SLOT = 16384 + 8192;

#define ASTG(SL)                                     \
  {                                                  \
    f16* d = lds + (SL) * SLOT + t * 8;              \
    gload16(aP0, d);                                 \
    gload16(aP1, d + 4096);                          \
    gload16(aP2, d + 8192);                          \
    gload16(aP3, d + 12288);                         \
  }
#define BSTG(SL)                                     \
  {                                                  \
    f16* d = lds + (SL) * SLOT + 16384 + t * 8;      \
    gload16(bP0, d);                                 \
    gload16(bP1, d + 4096);                          \
  }
#define AADV { aP0 += 64; aP1 += 64; aP2 += 64; aP3 += 64; }
#define BADV { bP0 += 64; bP1 += 64; }
#define VM2 asm volatile("s_waitcnt vmcnt(2)" ::: "memory")
#define LDA_(MH)                                     \
  _Pragma("unroll") for (int mi = 0; mi < 4; ++mi)   \
  _Pragma("unroll") for (int kh = 0; kh < 2; ++kh)   \
      fa[mi][kh] = *(const f16x8*)(LA + aof[MH][mi][kh]);
#define LDB_(NH)                                     \
  _Pragma("unroll") for (int kh = 0; kh < 2; ++kh)   \
      fb[NH][kh] = *(const f16x8*)(LBp + bof[NH][kh]);
#define MFM_(MH, NH)                                                        \
  _Pragma("unroll") for (int mi = 0; mi < 4; ++mi)                          \
  _Pragma("unroll") for (int kh = 0; kh < 2; ++kh)                          \
      acc[((MH)*4 + mi) * 2 + (NH)] =                                       \
          __builtin_amdgcn_mfma_f32_16x16x32_f16(                           \
              fa[mi][kh], fb[NH][kh], acc[((MH)*4 + mi) * 2 + (NH)], 0, 0, 0);
#define AWR(MH)                                                             \
  if (wn == 0 && (kt >> 2) == by) {                                         \
    _Pragma("unroll") for (int mi = 0; mi < 4; ++mi)                        \
    _Pragma("unroll") for (int kh = 0; kh < 2; ++kh) {                      \
      const int grow = bx * 256 + wm * 128 + (MH) * 64 + mi * 16 + fr;      \
      const int kc = kt * 64 + (g0 + kh * 4) * 8;                           \
      const float is = is8[MH][mi];                                         \
      float* dst = Ab + (size_t)grow * 2048 + kc;                           \
      f32x4 o0 = {(float)fa[mi][kh][0] * is, (float)fa[mi][kh][1] * is,     \
                  (float)fa[mi][kh][2] * is, (float)fa[mi][kh][3] * is};    \
      f32x4 o1 = {(float)fa[mi][kh][4] * is, (float)fa[mi][kh][5] * is,     \
                  (float)fa[mi][kh][6] * is, (float)fa[mi][kh][7] * is};    \
      *(f32x4*)dst = o0;                                                    \
      *(f32x4*)(dst + 4) = o1;                                              \
    }                                                                       \
  }

  ASTG(0); AADV;
  BSTG(0); BADV;
  BSTG(1); BADV;
  VM2;
  BARF;

#pragma unroll 1
  for (int kt = 0; kt < 32; ++kt) {
    const int sl = kt & 1;
    const f16* LA = lds + sl * SLOT;
    const f16* LBp = LA + 16384;
    // phase 1
    ASTG(sl ^ 1);
    if (kt + 2 < 32) AADV;
    LDA_(0); LDB_(0); LDB_(1);
    PRIO1; MFM_(0, 0); MFM_(0, 1); PRIO0;
    AWR(0);
    BARF;
    // phase 2
    LDA_(1);
    BSTG(sl);
    if (kt + 3 < 32) BADV;
    VM2;
    PRIO1; MFM_(1, 0); MFM_(1, 1); PRIO0;
    AWR(1);
    BARF;
  }
#undef ASTG
#undef BSTG
#undef AADV
#undef BADV
#undef VM2
#undef LDA_
#undef LDB_
#undef MFM_
#undef AWR

  f16* Cb = attb + ((size_t)b << 21);
  const int col = by * 128 + wn * 32 + fr * 2;
#pragma unroll
  for (int mi = 0; mi < 8; ++mi)
#pragma unroll
    for (int q = 0; q < 4; ++q) {
      const int row = bx * 256 + wm * 128 + mi * 16 + g0 * 4 + q;
      const float is = 1.0f / sums_b[row];
      f16x2 o = {(f16)(acc[mi * 2 + 0][q] * is), (f16)(acc[mi * 2 + 1][q] * is)};
      *(f16x2*)(Cb + (size_t)row * 1024 + col) = o;
    }
}

// ----------------- merged prep: src cast (blocks 0..4095) + W^T cast (rest)
__global__ __launch_bounds__(256) void k_prep(
    const float* __restrict__ src, const float* __restrict__ w0,
    const float* __restrict__ w1, const float* __restrict__ w2,
    f16* __restrict__ srch, f16* __restrict__ wt)
{
  const int b = blockIdx.x, t = threadIdx.x;
  if (b < 4096) {
    const size_t i = (size_t)b * 256 + t;
    const float4* p = (const float4*)src;
    float4 v0 = p[2 * i], v1 = p[2 * i + 1];
    f16x8 o;
    o[0] = (f16)v0.x; o[1] = (f16)v0.y; o[2] = (f16)v0.z; o[3] = (f16)v0.w;
    o[4] = (f16)v1.x; o[5] = (f16)v1.y; o[6] = (f16)v1.z; o[7] = (f16)v1.w;
    *(f16x8*)(srch + 8 * i) = o;
    return;
  }
  const int id = b - 4096;            // 0..767
  const int z = id >> 8, rem = id & 255;
  const int bx = rem & 15, by = rem >> 4;
  const float* in = (z == 0) ? w0 : (z == 1 ? w1 : w2);
  f16* o = wt + ((size_t)z << 20);
  __shared__ f16 tile[64][65];
  const int rr = t >> 4, c4 = (t & 15) * 4;
  const int r0 = bx * 64, c0 = by * 64;
#pragma unroll
  for (int i = 0; i < 4; ++i) {
    float4 f = *(const float4*)(in + (size_t)(r0 + rr + 16 * i) * 1024 + c0 + c4);
    tile[rr + 16 * i][c4 + 0] = (f16)f.x;
    tile[rr + 16 * i][c4 + 1] = (f16)f.y;
    tile[rr + 16 * i][c4 + 2] = (f16)f.z;
    tile[rr + 16 * i][c4 + 3] = (f16)f.w;
  }
  __syncthreads();
#pragma unroll
  for (int i = 0; i < 4; ++i) {
    const int n = c0 + rr + 16 * i;
    f16* dst = o + (size_t)n * 1024 + r0 + c4;
    dst[0] = tile[c4 + 0][rr + 16 * i];
    dst[1] = tile[c4 + 1][rr + 16 * i];
    dst[2] = tile[c4 + 2][rr + 16 * i];
    dst[3] = tile[c4 + 3][rr + 16 * i];
  }
}

// ---------- scramble-transpose of V (blocks 0..2047) + zero sums (block 2048)
__global__ __launch_bounds__(256) void k_scrT(const f16* __restrict__ vp,
                                              f16* __restrict__ vtT,
                                              float* __restrict__ sums)
{
  const int t = threadIdx.x;
  if (blockIdx.x == 2048) {
    f32x4 z = {0.f, 0.f, 0.f, 0.f};
#pragma unroll
    for (int i = 0; i < 8; ++i) ((f32x4*)sums)[t + i * 256] = z;
    return;
  }
  __shared__ f16 tile[64][68];
  const int id = blockIdx.x;
  const int sx = id & 31, sy = (id >> 5) & 15, bz = id >> 9;
  const int sp0 = sx * 64, dp0 = sy * 64;
  const int d6 = dp0 >> 6;
  const int jb = (sp0 >> 7) << 6;
  const int sbase = sp0 & 127;
  const f16* srcv = vp + ((size_t)bz << 21);
  f16* dstv = vtT + ((size_t)bz << 21);
#pragma unroll
  for (int p = 0; p < 2; ++p) {
    const int u = p * 32 + (t >> 3);
    const int s = ((sbase + u) << 4) | d6;
    const int cc = (t & 7) << 3;
    f16x8 v = *(const f16x8*)(srcv + (size_t)s * 1024 + jb + cc);
    *(f16x4*)&tile[u][cc]     = f16x4{v[0], v[1], v[2], v[3]};
    *(f16x4*)&tile[u][cc + 4] = f16x4{v[4], v[5], v[6], v[7]};
  }
  __syncthreads();
#pragma unroll
  for (int p = 0; p < 2; ++p) {
    const int cc = p * 32 + (t >> 3);
    const int v0 = (t & 7) << 3;
    f16x8 o;
#pragma unroll
    for (int j = 0; j < 8; ++j) o[j] = tile[v0 + j][cc];
    *(f16x8*)(dstv + (size_t)(dp0 + cc) * 2048 + sp0 + v0) = o;
  }
}

// --------------------------------------------- fused LN1 + add + LN2
__global__ __launch_bounds__(256) void k_ln(
    const f16* __restrict__ attb, const float* __restrict__ src,
    const float* __restrict__ w1, const float* __restrict__ b1,
    const float* __restrict__ w2, const float* __restrict__ b2,
    float* __restrict__ out)
{
  const size_t base = (size_t)blockIdx.x * 1024;
  const int t = threadIdx.x, lane = t & 63, w = t >> 6;
  f16x4 a4 = ((const f16x4*)(attb + base))[t];
  float ax = (float)a4[0], ay = (float)a4[1], az = (float)a4[2], aw = (float)a4[3];
  float s = ax + ay + az + aw;
  float s2 = ax * ax + ay * ay + az * az + aw * aw;
#pragma unroll
  for (int off = 1; off < 64; off <<= 1) {
    s += __shfl_xor(s, off);
    s2 += __shfl_xor(s2, off);
  }
  __shared__ float red[16];
  if (lane == 0) { red[w] = s; red[4 + w] = s2; }
  __syncthreads();
  s = red[0] + red[1] + red[2] + red[3];
  s2 = red[4] + red[5] + red[6] + red[7];
  float mu = s * (1.0f / 1024.0f);
  float var = s2 * (1.0f / 1024.0f) - mu * mu;
  float rs = rsqrtf(var + 1e-5f);
  float4 W1 = ((const float4*)w1)[t], B1 = ((const float4*)b1)[t];
  float4 sv = ((const float4*)(src + base))[t];
  float y0 = sv.x + (ax - mu) * rs * W1.x + B1.x;
  float y1 = sv.y + (ay - mu) * rs * W1.y + B1.y;
  float y2 = sv.z + (az - mu) * rs * W1.z + B1.z;
  float y3 = sv.w + (aw - mu) * rs * W1.w + B1.w;
  s = y0 + y1 + y2 + y3;
  s2 = y0 * y0 + y1 * y1 + y2 * y2 + y3 * y3;
#pragma unroll
  for (int off = 1; off < 64; off <<= 1) {
    s += __shfl_xor(s, off);
    s2 += __shfl_xor(s2, off);
  }
  if (lane == 0) { red[8 + w] = s; red[12 + w] = s2; }
  __syncthreads();
  s = red[8] + red[9] + red[10] + red[11];
  s2 = red[12] + red[13] + red[14] + red[15];
  mu = s * (1.0f / 1024.0f);
  var = s2 * (1.0f / 1024.0f) - mu * mu;
  rs = rsqrtf(var + 1e-5f);
  float4 W2 = ((const float4*)w2)[t], B2 = ((const float4*)b2)[t];
  float4 o;
  o.x = (y0 - mu) * rs * W2.x + B2.x;
  o.y = (y1 - mu) * rs * W2.y + B2.y;
  o.z = (y2 - mu) * rs * W2.z + B2.z;
  o.w = (y3 - mu) * rs * W2.w + B2.w;
  ((float4*)(out + base))[t] = o;
}

// ---------------------------------------------------------------- launch
extern "C" void kernel_launch(void* const* d_in, const int* in_sizes, int n_in,
                              void* d_out, int out_size, void* d_ws, size_t ws_size,
                              hipStream_t stream) {
  const float* src = (const float*)d_in[0];
  const float* Wq  = (const float*)d_in[1];
  const float* Wk  = (const float*)d_in[2];
  const float* Wv  = (const float*)d_in[3];
  const float* l1w = (const float*)d_in[4];
  const float* l1b = (const float*)d_in[5];
  const float* l2w = (const float*)d_in[6];
  const float* l2b = (const float*)d_in[7];
  float* Xout = (float*)d_out;
  float* Aout = Xout + (size_t)NROWS * D_MODEL;

  // workspace layout (134 MB)
  char* ws = (char*)d_ws;
  f16* srch = (f16*)ws;                       // 16 MB (8192x1024); dead after qkv
  float* sums = (float*)ws;                   // 32 KB (overlays dead srch)
  f16* wt   = (f16*)(ws + (16u << 20));       //  6 MB (3072x1024, W^T)
  f16* qp   = (f16*)(ws + (22u << 20));       // 16 MB
  f16* kp   = (f16*)(ws + (38u << 20));       // 16 MB
  f16* vp   = (f16*)(ws + (54u << 20));       // 16 MB
  f16* vtT  = (f16*)(ws + (70u << 20));       // 16 MB (B,D,S scrambled-T)
  f16* abf  = (f16*)(ws + (86u << 20));       // 32 MB (B,S,S e f16)
  f16* attb = (f16*)(ws + (118u << 20));      // 16 MB (B,S,D f16)

  k_prep<<<4864, 256, 0, stream>>>(src, Wq, Wk, Wv, srch, wt);
  k_qkv3<<<dim3(32, 24), 512, 0, stream>>>(srch, wt, qp, kp, vp);
  k_scrT<<<2049, 256, 0, stream>>>(vp, vtT, sums);   // + zeroes sums
  k_scores<<<256, 512, 0, stream>>>(qp, kp, abf, sums);
  k_att<<<256, 512, 0, stream>>>(abf, vtT, sums, attb, Aout);
  k_ln<<<NROWS, 256, 0, stream>>>(attb, src, l1w, l1b, l2w, l2b, Xout);
}